// Round 2
// baseline (404.034 us; speedup 1.0000x reference)
//
#include <hip/hip_runtime.h>
#include <cstdint>
#include <cstddef>

// Problem constants
#define T_TOKN 16
#define NUNITS 4096
#define LPATH  32
#define NPATHS 1024
#define BNUM   8

typedef __attribute__((ext_vector_type(8))) short short8;   // 8 bf16 in 4 VGPRs
typedef __attribute__((ext_vector_type(4))) short short4x;  // 4 bf16 in 2 VGPRs
typedef __attribute__((ext_vector_type(4))) float f32x4;    // MFMA accumulator

// ws float offsets
enum : size_t {
  OFF_WFRAG   = 0,                        // 524288 ushort: lstm W frags [tf|tb|pf|pb]
  OFF_LINFRAG = 262144,                   // 65536 ushort: lin/ul B-frags
  OFF_OUTF    = 294912,                   // token fwd h, bf16 16x4096x128
  OFF_OUTB    = OFF_OUTF + 4194304,       // token bwd h (time-realigned), bf16
  OFF_OUTLIN  = OFF_OUTB + 4194304,       // f32 16x4096x128
  OFF_SCORES  = OFF_OUTLIN + 8388608,     // f32 16x4096
  OFF_TOKFEAT = OFF_SCORES + 65536,       // f32 4096x128
  OFF_POUTF   = OFF_TOKFEAT + 524288,     // path fwd h, bf16 32x1024x128
  OFF_POUTB   = OFF_POUTF + 2097152,
  OFF_INT     = OFF_POUTB + 2097152,      // ints: tok_len 4096 | fe 1024 | p_len 1024 | off_p 1024 | un_p 1024
  WS_FLOATS   = OFF_INT + 8192
};

static __device__ __forceinline__ unsigned short f2bf(float f) {
  union { float f; unsigned u; } v; v.f = f;
  unsigned r = v.u + 0x7fffu + ((v.u >> 16) & 1u);
  return (unsigned short)(r >> 16);
}
static __device__ __forceinline__ float sigf(float x)      { return 1.f / (1.f + __expf(-x)); }
static __device__ __forceinline__ float tanhfast(float x)  { return 2.f / (1.f + __expf(-2.f * x)) - 1.f; }

// ---------------------------------------------------------------------------
// prep: (a) lstm W frags (NEW layout: per-wave 4-gate column slices);
//       (b) lin/ul B-frags; (c) lengths/path metadata
// wfrag layout (per matrix, 131072 ushort):
//   idx = (((w*4 + q)*8 + ks)*64 + lane)*8 + i
//   covers W row G = q*128 + w*16 + (lane&15), col k = ks*32 + (lane>>4)*8 + i
// so wave w holds ALL FOUR gates (q=0..3) for j in [w*16, w*16+16) -> the
// MFMA C-layout places i,f,g,o of cell (u,j) in one lane's registers.
// ---------------------------------------------------------------------------
__global__ void prep_kernel(
    const float* __restrict__ tWif, const float* __restrict__ tWhf,
    const float* __restrict__ tWib, const float* __restrict__ tWhb,
    const float* __restrict__ pWif, const float* __restrict__ pWhf,
    const float* __restrict__ pWib, const float* __restrict__ pWhb,
    const float* __restrict__ linW, const float* __restrict__ ulW,
    const int* __restrict__ units, const int* __restrict__ paths,
    const int* __restrict__ upd, const int* __restrict__ ppd,
    float* __restrict__ ws, int* __restrict__ ip)
{
  int idx = blockIdx.x * 256 + threadIdx.x;
  if (idx < 524288) {
    unsigned short* wf = (unsigned short*)(ws + OFF_WFRAG);
    int mat = idx >> 17, rem = idx & 131071;
    int i    = rem & 7;
    int lane = (rem >> 3) & 63;
    int ks   = (rem >> 9) & 7;
    int q    = (rem >> 12) & 3;
    int w    = (rem >> 14) & 7;
    int g = q * 128 + w * 16 + (lane & 15);
    int k = ks * 32 + ((lane >> 4) << 3) + i;
    const float* Wi; const float* Wh;
    switch (mat) {
      case 0: Wi = tWif; Wh = tWhf; break;
      case 1: Wi = tWib; Wh = tWhb; break;
      case 2: Wi = pWif; Wh = pWhf; break;
      default: Wi = pWib; Wh = pWhb; break;
    }
    float v = (k < 128) ? Wi[g * 128 + k] : Wh[g * 128 + (k - 128)];
    wf[idx] = f2bf(v);
  } else if (idx < 524288 + 65536) {
    unsigned short* lf = (unsigned short*)(ws + OFF_LINFRAG);
    int i2 = idx - 524288;
    int mat = i2 >> 15, rem = i2 & 32767;
    int i  = rem & 7;
    int lane = (rem >> 3) & 63;
    int ks = (rem >> 9) & 7;
    int ct = (rem >> 12) & 7;
    int e = ct * 16 + (lane & 15);
    int k = ks * 32 + ((lane >> 4) << 3) + i;
    const float* W = mat ? ulW : linW;
    lf[i2] = f2bf(W[e * 256 + k]);
  } else if (idx < 589824 + 4096) {
    int n = idx - 589824;
    int len = T_TOKN;
    for (int t = 0; t < T_TOKN; ++t)
      if (units[t * NUNITS + n] == 0) { len = t; break; }
    ip[n] = len;                                   // tok_len
  } else if (idx < 589824 + 5120) {
    int p = idx - (589824 + 4096);
    int* fe_a  = ip + 4096;
    int* p_len = ip + 5120;
    int* off_p = ip + 6144;
    int* un_p  = ip + 7168;
    int cum = 0; int d = BNUM - 1;
    for (int dd = 0; dd < BNUM; ++dd) {
      int c2 = cum + ppd[dd];
      if (p < c2) { d = dd; break; }
      cum = c2;
    }
    int off = 0;
    for (int dd = 0; dd < d; ++dd) off += upd[dd];
    int un = upd[d];
    off_p[p] = off; un_p[p] = un;
    int f = LPATH;
    for (int t = 0; t < LPATH; ++t)
      if (paths[t * NPATHS + p] == -1) { f = t; break; }
    fe_a[p] = f;
    int pl = LPATH;
    for (int t = 0; t < LPATH; ++t) {
      int v = paths[t * NPATHS + p];
      if ((t >= f) || (v < 0) || (v > un)) { pl = t; break; }
    }
    p_len[p] = pl;
  }
}

// ---------------------------------------------------------------------------
// MFMA BiLSTM, 8-wave blocks (512 thr), resident B = 4 gate-tiles/wave
// (128 VGPR), all-gates-in-lane -> pointwise fully in registers.
// NO gates LDS buffer: removes GSTORE + gate loads + their bank conflicts
// (12.6M/dispatch in r1) and halves the A-tile broadcast (8 waves instead
// of 16 read the same fragments).
// 2-group ping-pong retained: even phase MFMA(A,t) || pointwise(B,t-1);
// odd phase MFMA(B,t) || pointwise(A,t). acc latency hides under the
// other group's transcendental chain. 2 barriers/step.
// MODE 0: token (emb gather), 32 units/block, grid(128,2) = 1 block/CU.
// MODE 1: path (tok_feat gather + keep mask), 32 paths/block, grid(32,2);
//         16 REAL rows per MFMA group (r1's 2x dummy-row waste gone).
// ---------------------------------------------------------------------------
template <int MODE>
__global__ __launch_bounds__(512, 2) void lstm_kernel(
    const unsigned short* __restrict__ wfragAll,
    const float* __restrict__ biasF, const float* __restrict__ biasB,
    const float* __restrict__ src,       // emb or tok_feat (f32)
    const int* __restrict__ idxsrc,      // units or paths
    const int* __restrict__ lens,        // tok_len or p_len
    const int* __restrict__ fe_a, const int* __restrict__ off_p, const int* __restrict__ un_p,
    unsigned short* __restrict__ outF, unsigned short* __restrict__ outB)
{
  constexpr int NN   = MODE ? NPATHS : NUNITS;
  constexpr int TT   = MODE ? LPATH : T_TOKN;
  constexpr int ASTR = 264;               // A-tile row stride (ushorts)

  __shared__ __align__(16) unsigned short ash[2][16 * ASTR]; // [u][0:128)=x [u][128:256)=h

  const int tid  = threadIdx.x;
  const int dir  = blockIdx.y;
  const int n0   = blockIdx.x * 32;
  const int lane = tid & 63, wv = tid >> 6;   // wv in [0,8)
  const int cl   = lane & 15, quad = lane >> 4;
  const int koq  = quad << 3;                 // k-slice (ushort) within 32
  const int jj   = wv * 16 + cl;              // this lane's hidden column j

  // ---- resident B frags: wave wv holds gates q=0..3 for j in [wv*16,+16) ----
  const unsigned short* wbase =
      wfragAll + (size_t)((MODE ? 2 : 0) + dir) * 131072;
  short8 bfr[8][4];
#pragma unroll
  for (int ks = 0; ks < 8; ++ks)
#pragma unroll
    for (int q = 0; q < 4; ++q)
      bfr[ks][q] = *(const short8*)&wbase[(((wv * 4 + q) * 8 + ks) * 64 + lane) * 8];

  const float* bcp = dir ? biasB : biasF;
  float bq[4];
#pragma unroll
  for (int q = 0; q < 4; ++q) bq[q] = bcp[q * 128 + jj];

  // ---- pointwise state: lane owns cells (u = quad*4+r, j = jj), 2 groups ----
  float cs0[4], cs1[4];
  int   pl0[4], pl1[4];
#pragma unroll
  for (int r = 0; r < 4; ++r) {
    cs0[r] = 0.f; cs1[r] = 0.f;
    pl0[r] = lens[n0 + quad * 4 + r];
    pl1[r] = lens[n0 + 16 + quad * 4 + r];
  }

  // ---- gather state: thread = (row, 4-col slice) ----
  const int grow = tid >> 5;           // 0..15
  const int gc0  = (tid & 31) * 4;     // 0..124
  const int gn0 = n0 + grow, gn1 = n0 + 16 + grow;
  const int glen0 = lens[gn0], glen1 = lens[gn1];
  int gfe0 = 0, goff0 = 0, gun0 = 0, gfe1 = 0, goff1 = 0, gun1 = 0;
  if constexpr (MODE) {
    gfe0 = fe_a[gn0]; goff0 = off_p[gn0]; gun0 = un_p[gn0];
    gfe1 = fe_a[gn1]; goff1 = off_p[gn1]; gun1 = un_p[gn1];
  }
  float4 xq0, xq1;

#define XLOAD(G, XQ, TN) do {                                                 \
    int tc = (TN); if (tc > TT - 1) tc = TT - 1;                              \
    int tau = dir ? min(max(glen##G - 1 - tc, 0), TT - 1) : tc;               \
    if constexpr (MODE == 0) {                                                \
      int tok = idxsrc[tau * NN + gn##G];                                     \
      XQ = *(const float4*)&src[(size_t)tok * 128 + gc0];                     \
    } else {                                                                  \
      int v = idxsrc[tau * NN + gn##G];                                       \
      bool keep = (tau < gfe##G) && (v >= 0) && (v < gun##G);                 \
      if (keep)                                                               \
        XQ = *(const float4*)&src[(size_t)min(v + goff##G, NUNITS - 1) * 128 + gc0]; \
      else { XQ.x = 0.f; XQ.y = 0.f; XQ.z = 0.f; XQ.w = 0.f; }                \
    }                                                                         \
  } while (0)

#define XWRITE(G, XQ) do {                                                    \
    short4x xv;                                                               \
    xv[0] = (short)f2bf(XQ.x); xv[1] = (short)f2bf(XQ.y);                     \
    xv[2] = (short)f2bf(XQ.z); xv[3] = (short)f2bf(XQ.w);                     \
    *(short4x*)&ash[G][grow * ASTR + gc0] = xv;                               \
  } while (0)

#define MFMA_G(G, ACC) do {                                                   \
    _Pragma("unroll")                                                         \
    for (int q = 0; q < 4; ++q) { f32x4 z = {0.f, 0.f, 0.f, 0.f}; ACC[q] = z; } \
    _Pragma("unroll")                                                         \
    for (int ks = 0; ks < 8; ++ks) {                                          \
      short8 afr = *(const short8*)&ash[G][cl * ASTR + ks * 32 + koq];        \
      ACC[0] = __builtin_amdgcn_mfma_f32_16x16x32_bf16(afr, bfr[ks][0], ACC[0], 0, 0, 0); \
      ACC[1] = __builtin_amdgcn_mfma_f32_16x16x32_bf16(afr, bfr[ks][1], ACC[1], 0, 0, 0); \
      ACC[2] = __builtin_amdgcn_mfma_f32_16x16x32_bf16(afr, bfr[ks][2], ACC[2], 0, 0, 0); \
      ACC[3] = __builtin_amdgcn_mfma_f32_16x16x32_bf16(afr, bfr[ks][3], ACC[3], 0, 0, 0); \
    }                                                                         \
  } while (0)

#define PW(G, ACC, CST, PLEN, TPW) do {                                       \
    int tpw = (TPW);                                                          \
    _Pragma("unroll")                                                         \
    for (int r = 0; r < 4; ++r) {                                             \
      float iv = sigf(ACC[0][r] + bq[0]);                                     \
      float fv = sigf(ACC[1][r] + bq[1]);                                     \
      float gv = tanhfast(ACC[2][r] + bq[2]);                                 \
      float ov = sigf(ACC[3][r] + bq[3]);                                     \
      float c = fv * CST[r] + iv * gv;                                        \
      CST[r] = c;                                                             \
      unsigned short hb = f2bf(ov * tanhfast(c));                             \
      int u = quad * 4 + r;                                                   \
      ash[G][u * ASTR + 128 + jj] = hb;   /* h(t) for next MFMA (garbage for dead rows is bounded, outputs masked) */ \
      int L = PLEN[r];                                                        \
      int n = n0 + (G) * 16 + u;                                              \
      bool vld = tpw < L;                                                     \
      if (dir == 0) {                                                         \
        outF[((size_t)tpw * NN + n) * 128 + jj] = vld ? hb : (unsigned short)0; \
      } else {                                                                \
        size_t tr = vld ? (size_t)(L - 1 - tpw) : (size_t)tpw;                \
        outB[(tr * NN + n) * 128 + jj] = vld ? hb : (unsigned short)0;        \
      }                                                                       \
    }                                                                         \
  } while (0)

  // ---- zero A-tiles (h region + everything; x rows overwritten) ----
  for (int i = tid; i < 2 * 16 * ASTR / 2; i += 512) ((unsigned*)ash)[i] = 0u;
  XLOAD(0, xq0, 0);
  XLOAD(1, xq1, 0);
  __syncthreads();   // zero visible before x write
  XWRITE(0, xq0);
  __syncthreads();   // x(A,0) visible

  f32x4 acc0[4], acc1[4];

#pragma unroll 1
  for (int t = 0; t < TT; ++t) {
    // ===== even phase: MFMA A(t) || pointwise B(t-1) =====
    MFMA_G(0, acc0);
    if (t > 0) PW(1, acc1, cs1, pl1, t - 1);   // fills MFMA shadow
    XWRITE(1, xq1);                            // x(B,t) (ash[1] only)
    if (t + 1 < TT) XLOAD(0, xq0, t + 1);      // prefetch next A x
    __syncthreads();

    // ===== odd phase: MFMA B(t) || pointwise A(t) =====
    MFMA_G(1, acc1);
    PW(0, acc0, cs0, pl0, t);
    if (t + 1 < TT) { XWRITE(0, xq0); XLOAD(1, xq1, t + 1); }
    __syncthreads();
  }
  // ===== epilogue =====
  PW(1, acc1, cs1, pl1, TT - 1);

#undef XLOAD
#undef XWRITE
#undef MFMA_G
#undef PW
}

// ---------------------------------------------------------------------------
// MFMA GEMM: rows x 128, K=256, A = bf16 [INf|INb] from global, B resident
// (64 VGPR/lane, 4 waves cover 128 cols).  C+bias -> LDS tile -> epilogue.
// EPI 0: row-validity mask on A (invalid rows -> OUT = bias), f32 store.
// EPI 1: store OUT + fused LayerNorm+tanh+attention scores.
// ---------------------------------------------------------------------------
template <int EPI>
__global__ __launch_bounds__(256) void gemm_mfma(
    const unsigned short* __restrict__ INf, const unsigned short* __restrict__ INb,
    const int* __restrict__ lens,
    const unsigned short* __restrict__ Bfrag, const float* __restrict__ bias,
    float* __restrict__ OUT, float* __restrict__ scores,
    const float* __restrict__ lng, const float* __restrict__ lnb,
    const float* __restrict__ attw, const float* __restrict__ attb,
    const int* __restrict__ units, int Nn)
{
  constexpr int OSTR = 132;
  __shared__ float outs[64 * OSTR];
  __shared__ float red1[256];
  __shared__ float red2[256];
  __shared__ float rowm[64], rowr[64];
  __shared__ float awsh[128], lgsh[128], lbsh[128];

  int tid = threadIdx.x, lane = tid & 63, wv = tid >> 6;
  int row0 = blockIdx.x * 64;
  int t = row0 / Nn, n0 = row0 % Nn;   // 64-row blocks never straddle t

  if (EPI == 1 && tid < 128) {
    awsh[tid] = attw[tid]; lgsh[tid] = lng[tid]; lbsh[tid] = lnb[tid];
  }

  short8 bfr[8][2];
#pragma unroll
  for (int ks = 0; ks < 8; ++ks)
#pragma unroll
    for (int c2 = 0; c2 < 2; ++c2) {
      int ct = wv * 2 + c2;
      bfr[ks][c2] = *(const short8*)&Bfrag[(((ct * 8 + ks) * 64) + lane) * 8];
    }

  int rb = lane & 15;
  int koq = (lane >> 4) << 3;
  bool val[4];
#pragma unroll
  for (int rt = 0; rt < 4; ++rt)
    val[rt] = (EPI == 1) ? true : (t < lens[n0 + rt * 16 + rb]);

  f32x4 acc[4][2];
#pragma unroll
  for (int rt = 0; rt < 4; ++rt)
#pragma unroll
    for (int c2 = 0; c2 < 2; ++c2) {
      f32x4 z = {0.f, 0.f, 0.f, 0.f};
      acc[rt][c2] = z;
    }

#pragma unroll
  for (int ks = 0; ks < 8; ++ks) {
    const unsigned short* P = (ks < 4) ? INf : INb;
    int koff = (ks & 3) * 32 + koq;
#pragma unroll
    for (int rt = 0; rt < 4; ++rt) {
      short8 a = {0, 0, 0, 0, 0, 0, 0, 0};
      if (val[rt])
        a = *(const short8*)&P[((size_t)(row0 + rt * 16 + rb)) * 128 + koff];
#pragma unroll
      for (int c2 = 0; c2 < 2; ++c2)
        acc[rt][c2] = __builtin_amdgcn_mfma_f32_16x16x32_bf16(
            a, bfr[ks][c2], acc[rt][c2], 0, 0, 0);
    }
  }

  float bc[2];
#pragma unroll
  for (int c2 = 0; c2 < 2; ++c2) bc[c2] = bias[wv * 32 + c2 * 16 + rb];
#pragma unroll
  for (int rt = 0; rt < 4; ++rt)
#pragma unroll
    for (int c2 = 0; c2 < 2; ++c2) {
      int col = wv * 32 + c2 * 16 + rb;
      int ub  = rt * 16 + ((lane >> 4) << 2);
#pragma unroll
      for (int r = 0; r < 4; ++r)
        outs[(ub + r) * OSTR + col] = acc[rt][c2][r] + bc[c2];
    }
  __syncthreads();

  int row = tid >> 2, seg = tid & 3;
  const float* rp = &outs[row * OSTR + seg * 32];
  size_t go = ((size_t)(row0 + row)) * 128 + seg * 32;

  if (EPI == 0) {
#pragma unroll
    for (int x = 0; x < 8; ++x)
      *(f32x4*)&OUT[go + x * 4] = *(const f32x4*)&rp[x * 4];
  } else {
    f32x4 v[8];
    float s = 0.f, s2 = 0.f;
#pragma unroll
    for (int x = 0; x < 8; ++x) {
      v[x] = *(const f32x4*)&rp[x * 4];
#pragma unroll
      for (int c = 0; c < 4; ++c) { s += v[x][c]; s2 += v[x][c] * v[x][c]; }
    }
    red1[tid] = s; red2[tid] = s2;
    __syncthreads();
    if (tid < 64) {
      float a = red1[tid * 4] + red1[tid * 4 + 1] + red1[tid * 4 + 2] + red1[tid * 4 + 3];
      float b = red2[tid * 4] + red2[tid * 4 + 1] + red2[tid * 4 + 2] + red2[tid * 4 + 3];
      float m = a * (1.f / 128.f);
      float var = b * (1.f / 128.f) - m * m;
      rowm[tid] = m;
      rowr[tid] = rsqrtf(var + 1e-5f);
    }
    __syncthreads();
    float m = rowm[row], rs = rowr[row];
    float sp = 0.f;
#pragma unroll
    for (int x = 0; x < 8; ++x) {
#pragma unroll
      for (int c = 0; c < 4; ++c) {
        int col = seg * 32 + x * 4 + c;
        float q = tanhfast((v[x][c] - m) * rs * lgsh[col] + lbsh[col]);
        sp += q * awsh[col];
      }
      *(f32x4*)&OUT[go + x * 4] = v[x];
    }
    red1[tid] = sp;
    __syncthreads();
    if (tid < 64) {
      float s3 = red1[tid * 4] + red1[tid * 4 + 1] + red1[tid * 4 + 2] + red1[tid * 4 + 3]
               + attb[0];
      int n = n0 + tid;
      if (units[t * NUNITS + n] == 0) s3 = -1e9f;
      scores[t * NUNITS + n] = s3;
    }
  }
}

// ---------------------------------------------------------------------------
// Softmax over T=16 + attention-weighted pooling -> tok_feat[n][e]
// ---------------------------------------------------------------------------
__global__ __launch_bounds__(128) void softmax_feat_kernel(
    const float* __restrict__ scores, const float* __restrict__ out_lin,
    float* __restrict__ tok_feat)
{
  int n = blockIdx.x;
  int e = threadIdx.x;
  float s[T_TOKN];
  float m = -1e30f;
#pragma unroll
  for (int t = 0; t < T_TOKN; ++t) { s[t] = scores[t * NUNITS + n]; m = fmaxf(m, s[t]); }
  float sum = 0.f;
#pragma unroll
  for (int t = 0; t < T_TOKN; ++t) { s[t] = expf(s[t] - m); sum += s[t]; }
  float inv = 1.f / sum;
  float a = 0.f;
#pragma unroll
  for (int t = 0; t < T_TOKN; ++t)
    a += s[t] * inv * out_lin[((size_t)t * NUNITS + n) * 128 + e];
  tok_feat[n * 128 + e] = a;
}

// ---------------------------------------------------------------------------
extern "C" void kernel_launch(void* const* d_in, const int* in_sizes, int n_in,
                              void* d_out, int out_size, void* d_ws, size_t ws_size,
                              hipStream_t stream)
{
  const int*   units = (const int*)d_in[0];
  const int*   paths = (const int*)d_in[1];
  const int*   upd   = (const int*)d_in[2];
  const int*   ppd   = (const int*)d_in[3];
  const float* emb   = (const float*)d_in[4];
  const float* tWif  = (const float*)d_in[5];
  const float* tWhf  = (const float*)d_in[6];
  const float* tbf   = (const float*)d_in[7];
  const float* tWib  = (const float*)d_in[8];
  const float* tWhb  = (const float*)d_in[9];
  const float* tbb   = (const float*)d_in[10];
  const float* linW  = (const float*)d_in[11];
  const float* linb  = (const float*)d_in[12];
  const float* lng   = (const float*)d_in[13];
  const float* lnb   = (const float*)d_in[14];
  const float* attw  = (const float*)d_in[15];
  const float* attb  = (const float*)d_in[16];
  const float* pWif  = (const float*)d_in[17];
  const float* pWhf  = (const float*)d_in[18];
  const float* pbf   = (const float*)d_in[19];
  const float* pWib  = (const float*)d_in[20];
  const float* pWhb  = (const float*)d_in[21];
  const float* pbb   = (const float*)d_in[22];
  const float* ulW   = (const float*)d_in[23];
  const float* ulb   = (const float*)d_in[24];

  float* ws = (float*)d_ws;
  int*   ip = (int*)(ws + OFF_INT);
  if (ws_size < WS_FLOATS * sizeof(float)) return;

  unsigned short* wfrag   = (unsigned short*)(ws + OFF_WFRAG);
  unsigned short* linfrag = (unsigned short*)(ws + OFF_LINFRAG);
  unsigned short* ulfrag  = linfrag + 32768;
  unsigned short* OUTF  = (unsigned short*)(ws + OFF_OUTF);
  unsigned short* OUTB  = (unsigned short*)(ws + OFF_OUTB);
  unsigned short* POUTF = (unsigned short*)(ws + OFF_POUTF);
  unsigned short* POUTB = (unsigned short*)(ws + OFF_POUTB);

  prep_kernel<<<2324, 256, 0, stream>>>(tWif, tWhf, tWib, tWhb,
                                        pWif, pWhf, pWib, pWhb,
                                        linW, ulW, units, paths, upd, ppd,
                                        ws, ip);

  lstm_kernel<0><<<dim3(128, 2), 512, 0, stream>>>(
      wfrag, tbf, tbb, emb, units, ip /*tok_len*/, nullptr, nullptr, nullptr,
      OUTF, OUTB);

  gemm_mfma<1><<<1024, 256, 0, stream>>>(
      OUTF, OUTB, ip /*tok_len*/, linfrag, linb,
      ws + OFF_OUTLIN, ws + OFF_SCORES, lng, lnb, attw, attb, units, NUNITS);

  softmax_feat_kernel<<<4096, 128, 0, stream>>>(ws + OFF_SCORES, ws + OFF_OUTLIN,
                                                ws + OFF_TOKFEAT);

  lstm_kernel<1><<<dim3(32, 2), 512, 0, stream>>>(
      wfrag, pbf, pbb, ws + OFF_TOKFEAT, paths, ip + 5120 /*p_len*/,
      ip + 4096 /*fe*/, ip + 6144 /*off_p*/, ip + 7168 /*un_p*/,
      POUTF, POUTB);

  gemm_mfma<0><<<512, 256, 0, stream>>>(
      POUTF, POUTB, ip + 5120 /*p_len*/, ulfrag, ulb,
      (float*)d_out, nullptr, nullptr, nullptr, nullptr, nullptr, nullptr, NPATHS);
}

// Round 3
// 370.644 us; speedup vs baseline: 1.0901x; 1.0901x over previous
//
#include <hip/hip_runtime.h>
#include <cstdint>
#include <cstddef>

// Problem constants
#define T_TOKN 16
#define NUNITS 4096
#define LPATH  32
#define NPATHS 1024
#define BNUM   8

typedef __attribute__((ext_vector_type(8))) short short8;   // 8 bf16 in 4 VGPRs
typedef __attribute__((ext_vector_type(4))) short short4x;  // 4 bf16 in 2 VGPRs
typedef __attribute__((ext_vector_type(4))) float f32x4;    // MFMA accumulator

// ws float offsets
enum : size_t {
  OFF_WFRAG   = 0,                        // 524288 ushort: lstm W frags [tf|tb|pf|pb]
  OFF_LINFRAG = 262144,                   // 65536 ushort: lin/ul B-frags
  OFF_OUTF    = 294912,                   // token fwd h, bf16 16x4096x128
  OFF_OUTB    = OFF_OUTF + 4194304,       // token bwd h (time-realigned), bf16
  OFF_OUTLIN  = OFF_OUTB + 4194304,       // f32 16x4096x128
  OFF_SCORES  = OFF_OUTLIN + 8388608,     // f32 16x4096
  OFF_TOKFEAT = OFF_SCORES + 65536,       // f32 4096x128
  OFF_POUTF   = OFF_TOKFEAT + 524288,     // path fwd h, bf16 32x1024x128
  OFF_POUTB   = OFF_POUTF + 2097152,
  OFF_INT     = OFF_POUTB + 2097152,      // ints: tok_len 4096 | fe 1024 | p_len 1024 | off_p 1024 | un_p 1024
  WS_FLOATS   = OFF_INT + 8192
};

static __device__ __forceinline__ unsigned short f2bf(float f) {
  union { float f; unsigned u; } v; v.f = f;
  unsigned r = v.u + 0x7fffu + ((v.u >> 16) & 1u);
  return (unsigned short)(r >> 16);
}
static __device__ __forceinline__ float sigf(float x)      { return 1.f / (1.f + __expf(-x)); }
static __device__ __forceinline__ float tanhfast(float x)  { return 2.f / (1.f + __expf(-2.f * x)) - 1.f; }

// ---------------------------------------------------------------------------
// prep: (a) lstm W frags (per-wave 4-gate column slices);
//       (b) lin/ul B-frags; (c) lengths/path metadata
// wfrag layout (per matrix, 131072 ushort):
//   idx = (((w*4 + q)*8 + ks)*64 + lane)*8 + i
//   covers W row G = q*128 + w*16 + (lane&15), col k = ks*32 + (lane>>4)*8 + i
// so wave w holds ALL FOUR gates (q=0..3) for j in [w*16, w*16+16) -> the
// MFMA C-layout places i,f,g,o of cell (u,j) in one lane's registers.
// ---------------------------------------------------------------------------
__global__ void prep_kernel(
    const float* __restrict__ tWif, const float* __restrict__ tWhf,
    const float* __restrict__ tWib, const float* __restrict__ tWhb,
    const float* __restrict__ pWif, const float* __restrict__ pWhf,
    const float* __restrict__ pWib, const float* __restrict__ pWhb,
    const float* __restrict__ linW, const float* __restrict__ ulW,
    const int* __restrict__ units, const int* __restrict__ paths,
    const int* __restrict__ upd, const int* __restrict__ ppd,
    float* __restrict__ ws, int* __restrict__ ip)
{
  int idx = blockIdx.x * 256 + threadIdx.x;
  if (idx < 524288) {
    unsigned short* wf = (unsigned short*)(ws + OFF_WFRAG);
    int mat = idx >> 17, rem = idx & 131071;
    int i    = rem & 7;
    int lane = (rem >> 3) & 63;
    int ks   = (rem >> 9) & 7;
    int q    = (rem >> 12) & 3;
    int w    = (rem >> 14) & 7;
    int g = q * 128 + w * 16 + (lane & 15);
    int k = ks * 32 + ((lane >> 4) << 3) + i;
    const float* Wi; const float* Wh;
    switch (mat) {
      case 0: Wi = tWif; Wh = tWhf; break;
      case 1: Wi = tWib; Wh = tWhb; break;
      case 2: Wi = pWif; Wh = pWhf; break;
      default: Wi = pWib; Wh = pWhb; break;
    }
    float v = (k < 128) ? Wi[g * 128 + k] : Wh[g * 128 + (k - 128)];
    wf[idx] = f2bf(v);
  } else if (idx < 524288 + 65536) {
    unsigned short* lf = (unsigned short*)(ws + OFF_LINFRAG);
    int i2 = idx - 524288;
    int mat = i2 >> 15, rem = i2 & 32767;
    int i  = rem & 7;
    int lane = (rem >> 3) & 63;
    int ks = (rem >> 9) & 7;
    int ct = (rem >> 12) & 7;
    int e = ct * 16 + (lane & 15);
    int k = ks * 32 + ((lane >> 4) << 3) + i;
    const float* W = mat ? ulW : linW;
    lf[i2] = f2bf(W[e * 256 + k]);
  } else if (idx < 589824 + 4096) {
    int n = idx - 589824;
    int len = T_TOKN;
    for (int t = 0; t < T_TOKN; ++t)
      if (units[t * NUNITS + n] == 0) { len = t; break; }
    ip[n] = len;                                   // tok_len
  } else if (idx < 589824 + 5120) {
    int p = idx - (589824 + 4096);
    int* fe_a  = ip + 4096;
    int* p_len = ip + 5120;
    int* off_p = ip + 6144;
    int* un_p  = ip + 7168;
    int cum = 0; int d = BNUM - 1;
    for (int dd = 0; dd < BNUM; ++dd) {
      int c2 = cum + ppd[dd];
      if (p < c2) { d = dd; break; }
      cum = c2;
    }
    int off = 0;
    for (int dd = 0; dd < d; ++dd) off += upd[dd];
    int un = upd[d];
    off_p[p] = off; un_p[p] = un;
    int f = LPATH;
    for (int t = 0; t < LPATH; ++t)
      if (paths[t * NPATHS + p] == -1) { f = t; break; }
    fe_a[p] = f;
    int pl = LPATH;
    for (int t = 0; t < LPATH; ++t) {
      int v = paths[t * NPATHS + p];
      if ((t >= f) || (v < 0) || (v > un)) { pl = t; break; }
    }
    p_len[p] = pl;
  }
}

// ---------------------------------------------------------------------------
// MFMA BiLSTM, 8-wave blocks (512 thr), resident B = 4 gate-tiles/wave
// (128 VGPR), all-gates-in-lane -> pointwise fully in registers.
// Round-3 fixes vs round 2 (which was store-drain-bound, occ 5.6%):
//  * PW writes h ONLY to LDS. Global h store is a STAGED COALESCED copy one
//    phase later (thread = row x 8B slice; 32 thr x 8B = 256B burst/row,
//    LDS read at conflict-free minimum). Removes 512 scattered 2B stores
//    per block-phase that each barrier's vmcnt(0) had to drain.
//  * MODE 1 grid restored to 256 blocks (GR=4 -> 8 paths/block); round 2's
//    64 blocks left 75% of CUs idle on the serial 32-step chain.
// 2-group ping-pong: even phase MFMA A(t) || PW B(t-1) || store A h(t-1);
// odd phase MFMA B(t) || PW A(t) || store B h(t-1). 2 barriers/step.
// MODE 0: token (emb gather), GR=16 -> 32 units/block, grid(128,2).
// MODE 1: path (tok_feat gather + keep mask), GR=4 -> 8 paths/block,
//         grid(128,2); tile rows >= GR are dead (x=0, h garbage-bounded,
//         never stored) — MFMA row waste is free at ~5% MfmaUtil.
// ---------------------------------------------------------------------------
template <int MODE>
__global__ __launch_bounds__(512, 2) void lstm_kernel(
    const unsigned short* __restrict__ wfragAll,
    const float* __restrict__ biasF, const float* __restrict__ biasB,
    const float* __restrict__ src,       // emb or tok_feat (f32)
    const int* __restrict__ idxsrc,      // units or paths
    const int* __restrict__ lens,        // tok_len or p_len
    const int* __restrict__ fe_a, const int* __restrict__ off_p, const int* __restrict__ un_p,
    unsigned short* __restrict__ outF, unsigned short* __restrict__ outB)
{
  constexpr int NN   = MODE ? NPATHS : NUNITS;
  constexpr int TT   = MODE ? LPATH : T_TOKN;
  constexpr int GR   = MODE ? 4 : 16;     // real sequences per group
  constexpr int ASTR = 264;               // A-tile row stride (ushorts)

  __shared__ __align__(16) unsigned short ash[2][16 * ASTR]; // [u][0:128)=x [u][128:256)=h

  const int tid  = threadIdx.x;
  const int dir  = blockIdx.y;
  const int n0   = blockIdx.x * (2 * GR);
  const int lane = tid & 63, wv = tid >> 6;   // wv in [0,8)
  const int cl   = lane & 15, quad = lane >> 4;
  const int koq  = quad << 3;                 // k-slice (ushort) within 32
  const int jj   = wv * 16 + cl;              // this lane's hidden column j

  // ---- resident B frags: wave wv holds gates q=0..3 for j in [wv*16,+16) ----
  const unsigned short* wbase =
      wfragAll + (size_t)((MODE ? 2 : 0) + dir) * 131072;
  short8 bfr[8][4];
#pragma unroll
  for (int ks = 0; ks < 8; ++ks)
#pragma unroll
    for (int q = 0; q < 4; ++q)
      bfr[ks][q] = *(const short8*)&wbase[(((wv * 4 + q) * 8 + ks) * 64 + lane) * 8];

  const float* bcp = dir ? biasB : biasF;
  float bq[4];
#pragma unroll
  for (int q = 0; q < 4; ++q) bq[q] = bcp[q * 128 + jj];

  // ---- pointwise state: lane owns cells (u = quad*4+r, j = jj), 2 groups ----
  float cs0[4] = {0.f, 0.f, 0.f, 0.f}, cs1[4] = {0.f, 0.f, 0.f, 0.f};

  // ---- gather state ----
  int grow, gcol;
  if constexpr (MODE == 0) { grow = tid >> 5; gcol = (tid & 31) * 4; } // 16 rows x 32 thr x f32x4
  else                     { grow = tid >> 7; gcol = tid & 127; }      // 4 rows x 128 thr x f32
  const int gn0 = n0 + grow, gn1 = n0 + GR + grow;
  const int glen0 = lens[gn0], glen1 = lens[gn1];
  int gfe0 = 0, goff0 = 0, gun0 = 0, gfe1 = 0, goff1 = 0, gun1 = 0;
  if constexpr (MODE) {
    gfe0 = fe_a[gn0]; goff0 = off_p[gn0]; gun0 = un_p[gn0];
    gfe1 = fe_a[gn1]; goff1 = off_p[gn1]; gun1 = un_p[gn1];
  }
  float4 xq0, xq1;   // MODE 0 prefetch regs
  float  xs0, xs1;   // MODE 1 prefetch regs

  // ---- store state: thread = (row su, 8B slice sc); coalesced 256B/row ----
  const int su = tid >> 5, sc = (tid & 31) * 4;   // sc in ushorts
  const bool sv = su < GR;
  const int sn0 = n0 + (sv ? su : 0);
  const int sn1 = n0 + GR + (sv ? su : 0);
  const int sl0 = lens[sn0], sl1 = lens[sn1];

#define XLOAD(G, TN) do {                                                     \
    int tc = (TN); if (tc > TT - 1) tc = TT - 1;                              \
    int tau = dir ? min(max(glen##G - 1 - tc, 0), TT - 1) : tc;               \
    if constexpr (MODE == 0) {                                                \
      int tok = idxsrc[tau * NN + gn##G];                                     \
      xq##G = *(const float4*)&src[(size_t)tok * 128 + gcol];                 \
    } else {                                                                  \
      int v = idxsrc[tau * NN + gn##G];                                       \
      bool keep = (tau < gfe##G) && (v >= 0) && (v < gun##G);                 \
      xs##G = 0.f;                                                            \
      if (keep) xs##G = src[(size_t)min(v + goff##G, NUNITS - 1) * 128 + gcol]; \
    }                                                                         \
  } while (0)

#define XWRITE(G) do {                                                        \
    if constexpr (MODE == 0) {                                                \
      short4x xv;                                                             \
      xv[0] = (short)f2bf(xq##G.x); xv[1] = (short)f2bf(xq##G.y);             \
      xv[2] = (short)f2bf(xq##G.z); xv[3] = (short)f2bf(xq##G.w);             \
      *(short4x*)&ash[G][grow * ASTR + gcol] = xv;                            \
    } else {                                                                  \
      ash[G][grow * ASTR + gcol] = f2bf(xs##G);                               \
    }                                                                         \
  } while (0)

#define MFMA_G(G, ACC) do {                                                   \
    _Pragma("unroll")                                                         \
    for (int q = 0; q < 4; ++q) { f32x4 z = {0.f, 0.f, 0.f, 0.f}; ACC[q] = z; } \
    _Pragma("unroll")                                                         \
    for (int ks = 0; ks < 8; ++ks) {                                          \
      short8 afr = *(const short8*)&ash[G][cl * ASTR + ks * 32 + koq];        \
      ACC[0] = __builtin_amdgcn_mfma_f32_16x16x32_bf16(afr, bfr[ks][0], ACC[0], 0, 0, 0); \
      ACC[1] = __builtin_amdgcn_mfma_f32_16x16x32_bf16(afr, bfr[ks][1], ACC[1], 0, 0, 0); \
      ACC[2] = __builtin_amdgcn_mfma_f32_16x16x32_bf16(afr, bfr[ks][2], ACC[2], 0, 0, 0); \
      ACC[3] = __builtin_amdgcn_mfma_f32_16x16x32_bf16(afr, bfr[ks][3], ACC[3], 0, 0, 0); \
    }                                                                         \
  } while (0)

#define PW(G, ACC, CST) do {                                                  \
    _Pragma("unroll")                                                         \
    for (int r = 0; r < 4; ++r) {                                             \
      float iv = sigf(ACC[0][r] + bq[0]);                                     \
      float fv = sigf(ACC[1][r] + bq[1]);                                     \
      float gv = tanhfast(ACC[2][r] + bq[2]);                                 \
      float ov = sigf(ACC[3][r] + bq[3]);                                     \
      float c = fv * CST[r] + iv * gv;                                        \
      CST[r] = c;                                                             \
      ash[G][(quad * 4 + r) * ASTR + 128 + jj] = f2bf(ov * tanhfast(c));      \
    }                                                                         \
  } while (0)

// coalesced staged h store: reads other-phase-written ash[G].h (barrier-safe)
#define STOREH(G, TPW) do {                                                   \
    if (sv) {                                                                 \
      int tpw = (TPW);                                                        \
      uint2 hv = *(const uint2*)&ash[G][su * ASTR + 128 + sc];                \
      bool vld = tpw < sl##G;                                                 \
      uint2 o; o.x = vld ? hv.x : 0u; o.y = vld ? hv.y : 0u;                  \
      size_t tr = (dir && vld) ? (size_t)(sl##G - 1 - tpw) : (size_t)tpw;     \
      unsigned short* dst = dir ? outB : outF;                                \
      *(uint2*)&dst[(tr * NN + ((G) ? sn1 : sn0)) * 128 + sc] = o;            \
    }                                                                         \
  } while (0)

  // ---- zero A-tiles (x region of dead rows stays 0 forever) ----
  for (int i = tid; i < 2 * 16 * ASTR / 2; i += 512) ((unsigned*)ash)[i] = 0u;
  XLOAD(0, 0);
  XLOAD(1, 0);
  __syncthreads();   // zero visible before x write
  XWRITE(0);
  __syncthreads();   // x(A,0) visible

  f32x4 acc0[4], acc1[4];

#pragma unroll 1
  for (int t = 0; t < TT; ++t) {
    // ===== even phase: MFMA A(t) || PW B(t-1) || store A h(t-1) =====
    MFMA_G(0, acc0);
    if (t > 0) PW(1, acc1, cs1);         // writes ash1.h(t-1)
    XWRITE(1);                           // ash1.x(t)
    if (t + 1 < TT) XLOAD(0, t + 1);     // prefetch next A x
    if (t > 0) STOREH(0, t - 1);         // reads ash0.h(t-1) (written odd(t-1))
    __syncthreads();

    // ===== odd phase: MFMA B(t) || PW A(t) || store B h(t-1) =====
    MFMA_G(1, acc1);
    PW(0, acc0, cs0);                    // ash0.h(t)
    if (t + 1 < TT) { XWRITE(0); XLOAD(1, t + 1); }
    if (t > 0) STOREH(1, t - 1);         // reads ash1.h(t-1) (written even(t))
    __syncthreads();
  }
  // ===== epilogue =====
  PW(1, acc1, cs1);                      // ash1.h(TT-1)
  STOREH(0, TT - 1);                     // ash0.h(TT-1) visible from final barrier
  __syncthreads();
  STOREH(1, TT - 1);

#undef XLOAD
#undef XWRITE
#undef MFMA_G
#undef PW
#undef STOREH
}

// ---------------------------------------------------------------------------
// MFMA GEMM: rows x 128, K=256, A = bf16 [INf|INb] from global, B resident
// (64 VGPR/lane, 4 waves cover 128 cols).  C+bias -> LDS tile -> epilogue.
// EPI 0: row-validity mask on A (invalid rows -> OUT = bias), f32 store.
// EPI 1: store OUT + fused LayerNorm+tanh+attention scores.
// ---------------------------------------------------------------------------
template <int EPI>
__global__ __launch_bounds__(256) void gemm_mfma(
    const unsigned short* __restrict__ INf, const unsigned short* __restrict__ INb,
    const int* __restrict__ lens,
    const unsigned short* __restrict__ Bfrag, const float* __restrict__ bias,
    float* __restrict__ OUT, float* __restrict__ scores,
    const float* __restrict__ lng, const float* __restrict__ lnb,
    const float* __restrict__ attw, const float* __restrict__ attb,
    const int* __restrict__ units, int Nn)
{
  constexpr int OSTR = 132;
  __shared__ float outs[64 * OSTR];
  __shared__ float red1[256];
  __shared__ float red2[256];
  __shared__ float rowm[64], rowr[64];
  __shared__ float awsh[128], lgsh[128], lbsh[128];

  int tid = threadIdx.x, lane = tid & 63, wv = tid >> 6;
  int row0 = blockIdx.x * 64;
  int t = row0 / Nn, n0 = row0 % Nn;   // 64-row blocks never straddle t

  if (EPI == 1 && tid < 128) {
    awsh[tid] = attw[tid]; lgsh[tid] = lng[tid]; lbsh[tid] = lnb[tid];
  }

  short8 bfr[8][2];
#pragma unroll
  for (int ks = 0; ks < 8; ++ks)
#pragma unroll
    for (int c2 = 0; c2 < 2; ++c2) {
      int ct = wv * 2 + c2;
      bfr[ks][c2] = *(const short8*)&Bfrag[(((ct * 8 + ks) * 64) + lane) * 8];
    }

  int rb = lane & 15;
  int koq = (lane >> 4) << 3;
  bool val[4];
#pragma unroll
  for (int rt = 0; rt < 4; ++rt)
    val[rt] = (EPI == 1) ? true : (t < lens[n0 + rt * 16 + rb]);

  f32x4 acc[4][2];
#pragma unroll
  for (int rt = 0; rt < 4; ++rt)
#pragma unroll
    for (int c2 = 0; c2 < 2; ++c2) {
      f32x4 z = {0.f, 0.f, 0.f, 0.f};
      acc[rt][c2] = z;
    }

#pragma unroll
  for (int ks = 0; ks < 8; ++ks) {
    const unsigned short* P = (ks < 4) ? INf : INb;
    int koff = (ks & 3) * 32 + koq;
#pragma unroll
    for (int rt = 0; rt < 4; ++rt) {
      short8 a = {0, 0, 0, 0, 0, 0, 0, 0};
      if (val[rt])
        a = *(const short8*)&P[((size_t)(row0 + rt * 16 + rb)) * 128 + koff];
#pragma unroll
      for (int c2 = 0; c2 < 2; ++c2)
        acc[rt][c2] = __builtin_amdgcn_mfma_f32_16x16x32_bf16(
            a, bfr[ks][c2], acc[rt][c2], 0, 0, 0);
    }
  }

  float bc[2];
#pragma unroll
  for (int c2 = 0; c2 < 2; ++c2) bc[c2] = bias[wv * 32 + c2 * 16 + rb];
#pragma unroll
  for (int rt = 0; rt < 4; ++rt)
#pragma unroll
    for (int c2 = 0; c2 < 2; ++c2) {
      int col = wv * 32 + c2 * 16 + rb;
      int ub  = rt * 16 + ((lane >> 4) << 2);
#pragma unroll
      for (int r = 0; r < 4; ++r)
        outs[(ub + r) * OSTR + col] = acc[rt][c2][r] + bc[c2];
    }
  __syncthreads();

  int row = tid >> 2, seg = tid & 3;
  const float* rp = &outs[row * OSTR + seg * 32];
  size_t go = ((size_t)(row0 + row)) * 128 + seg * 32;

  if (EPI == 0) {
#pragma unroll
    for (int x = 0; x < 8; ++x)
      *(f32x4*)&OUT[go + x * 4] = *(const f32x4*)&rp[x * 4];
  } else {
    f32x4 v[8];
    float s = 0.f, s2 = 0.f;
#pragma unroll
    for (int x = 0; x < 8; ++x) {
      v[x] = *(const f32x4*)&rp[x * 4];
#pragma unroll
      for (int c = 0; c < 4; ++c) { s += v[x][c]; s2 += v[x][c] * v[x][c]; }
    }
    red1[tid] = s; red2[tid] = s2;
    __syncthreads();
    if (tid < 64) {
      float a = red1[tid * 4] + red1[tid * 4 + 1] + red1[tid * 4 + 2] + red1[tid * 4 + 3];
      float b = red2[tid * 4] + red2[tid * 4 + 1] + red2[tid * 4 + 2] + red2[tid * 4 + 3];
      float m = a * (1.f / 128.f);
      float var = b * (1.f / 128.f) - m * m;
      rowm[tid] = m;
      rowr[tid] = rsqrtf(var + 1e-5f);
    }
    __syncthreads();
    float m = rowm[row], rs = rowr[row];
    float sp = 0.f;
#pragma unroll
    for (int x = 0; x < 8; ++x) {
#pragma unroll
      for (int c = 0; c < 4; ++c) {
        int col = seg * 32 + x * 4 + c;
        float q = tanhfast((v[x][c] - m) * rs * lgsh[col] + lbsh[col]);
        sp += q * awsh[col];
      }
      *(f32x4*)&OUT[go + x * 4] = v[x];
    }
    red1[tid] = sp;
    __syncthreads();
    if (tid < 64) {
      float s3 = red1[tid * 4] + red1[tid * 4 + 1] + red1[tid * 4 + 2] + red1[tid * 4 + 3]
               + attb[0];
      int n = n0 + tid;
      if (units[t * NUNITS + n] == 0) s3 = -1e9f;
      scores[t * NUNITS + n] = s3;
    }
  }
}

// ---------------------------------------------------------------------------
// Softmax over T=16 + attention-weighted pooling -> tok_feat[n][e]
// ---------------------------------------------------------------------------
__global__ __launch_bounds__(128) void softmax_feat_kernel(
    const float* __restrict__ scores, const float* __restrict__ out_lin,
    float* __restrict__ tok_feat)
{
  int n = blockIdx.x;
  int e = threadIdx.x;
  float s[T_TOKN];
  float m = -1e30f;
#pragma unroll
  for (int t = 0; t < T_TOKN; ++t) { s[t] = scores[t * NUNITS + n]; m = fmaxf(m, s[t]); }
  float sum = 0.f;
#pragma unroll
  for (int t = 0; t < T_TOKN; ++t) { s[t] = expf(s[t] - m); sum += s[t]; }
  float inv = 1.f / sum;
  float a = 0.f;
#pragma unroll
  for (int t = 0; t < T_TOKN; ++t)
    a += s[t] * inv * out_lin[((size_t)t * NUNITS + n) * 128 + e];
  tok_feat[n * 128 + e] = a;
}

// ---------------------------------------------------------------------------
extern "C" void kernel_launch(void* const* d_in, const int* in_sizes, int n_in,
                              void* d_out, int out_size, void* d_ws, size_t ws_size,
                              hipStream_t stream)
{
  const int*   units = (const int*)d_in[0];
  const int*   paths = (const int*)d_in[1];
  const int*   upd   = (const int*)d_in[2];
  const int*   ppd   = (const int*)d_in[3];
  const float* emb   = (const float*)d_in[4];
  const float* tWif  = (const float*)d_in[5];
  const float* tWhf  = (const float*)d_in[6];
  const float* tbf   = (const float*)d_in[7];
  const float* tWib  = (const float*)d_in[8];
  const float* tWhb  = (const float*)d_in[9];
  const float* tbb   = (const float*)d_in[10];
  const float* linW  = (const float*)d_in[11];
  const float* linb  = (const float*)d_in[12];
  const float* lng   = (const float*)d_in[13];
  const float* lnb   = (const float*)d_in[14];
  const float* attw  = (const float*)d_in[15];
  const float* attb  = (const float*)d_in[16];
  const float* pWif  = (const float*)d_in[17];
  const float* pWhf  = (const float*)d_in[18];
  const float* pbf   = (const float*)d_in[19];
  const float* pWib  = (const float*)d_in[20];
  const float* pWhb  = (const float*)d_in[21];
  const float* pbb   = (const float*)d_in[22];
  const float* ulW   = (const float*)d_in[23];
  const float* ulb   = (const float*)d_in[24];

  float* ws = (float*)d_ws;
  int*   ip = (int*)(ws + OFF_INT);
  if (ws_size < WS_FLOATS * sizeof(float)) return;

  unsigned short* wfrag   = (unsigned short*)(ws + OFF_WFRAG);
  unsigned short* linfrag = (unsigned short*)(ws + OFF_LINFRAG);
  unsigned short* ulfrag  = linfrag + 32768;
  unsigned short* OUTF  = (unsigned short*)(ws + OFF_OUTF);
  unsigned short* OUTB  = (unsigned short*)(ws + OFF_OUTB);
  unsigned short* POUTF = (unsigned short*)(ws + OFF_POUTF);
  unsigned short* POUTB = (unsigned short*)(ws + OFF_POUTB);

  prep_kernel<<<2324, 256, 0, stream>>>(tWif, tWhf, tWib, tWhb,
                                        pWif, pWhf, pWib, pWhb,
                                        linW, ulW, units, paths, upd, ppd,
                                        ws, ip);

  lstm_kernel<0><<<dim3(128, 2), 512, 0, stream>>>(
      wfrag, tbf, tbb, emb, units, ip /*tok_len*/, nullptr, nullptr, nullptr,
      OUTF, OUTB);

  gemm_mfma<1><<<1024, 256, 0, stream>>>(
      OUTF, OUTB, ip /*tok_len*/, linfrag, linb,
      ws + OFF_OUTLIN, ws + OFF_SCORES, lng, lnb, attw, attb, units, NUNITS);

  softmax_feat_kernel<<<4096, 128, 0, stream>>>(ws + OFF_SCORES, ws + OFF_OUTLIN,
                                                ws + OFF_TOKFEAT);

  lstm_kernel<1><<<dim3(128, 2), 512, 0, stream>>>(
      wfrag, pbf, pbb, ws + OFF_TOKFEAT, paths, ip + 5120 /*p_len*/,
      ip + 4096 /*fe*/, ip + 6144 /*off_p*/, ip + 7168 /*un_p*/,
      POUTF, POUTB);

  gemm_mfma<0><<<512, 256, 0, stream>>>(
      POUTF, POUTB, ip + 5120 /*p_len*/, ulfrag, ulb,
      (float*)d_out, nullptr, nullptr, nullptr, nullptr, nullptr, nullptr, NPATHS);
}

// Round 4
// 317.665 us; speedup vs baseline: 1.2719x; 1.1668x over previous
//
#include <hip/hip_runtime.h>
#include <cstdint>
#include <cstddef>

// Problem constants
#define T_TOKN 16
#define NUNITS 4096
#define LPATH  32
#define NPATHS 1024
#define BNUM   8

typedef __attribute__((ext_vector_type(8))) short short8;   // 8 bf16 in 4 VGPRs
typedef __attribute__((ext_vector_type(4))) short short4x;  // 4 bf16 in 2 VGPRs
typedef __attribute__((ext_vector_type(4))) float f32x4;    // MFMA accumulator

// ws float offsets
enum : size_t {
  OFF_WFRAG   = 0,                        // 524288 ushort: lstm W frags [tf|tb|pf|pb]
  OFF_LINFRAG = 262144,                   // 65536 ushort: lin/ul B-frags
  OFF_OUTF    = 294912,                   // token fwd h, bf16 16x4096x128
  OFF_OUTB    = OFF_OUTF + 4194304,       // token bwd h (time-realigned), bf16
  OFF_OUTLIN  = OFF_OUTB + 4194304,       // f32 16x4096x128
  OFF_SCORES  = OFF_OUTLIN + 8388608,     // f32 16x4096
  OFF_TOKFEAT = OFF_SCORES + 65536,       // f32 4096x128
  OFF_POUTF   = OFF_TOKFEAT + 524288,     // path fwd h, bf16 32x1024x128
  OFF_POUTB   = OFF_POUTF + 2097152,
  OFF_INT     = OFF_POUTB + 2097152,      // ints: tok_len 4096 | fe 1024 | p_len 1024 | off_p 1024 | un_p 1024
  WS_FLOATS   = OFF_INT + 8192
};

static __device__ __forceinline__ unsigned short f2bf(float f) {
  union { float f; unsigned u; } v; v.f = f;
  unsigned r = v.u + 0x7fffu + ((v.u >> 16) & 1u);
  return (unsigned short)(r >> 16);
}
static __device__ __forceinline__ unsigned pack_bf(float a, float b) {
  return (unsigned)f2bf(a) | ((unsigned)f2bf(b) << 16);
}
static __device__ __forceinline__ float sigf(float x)      { return 1.f / (1.f + __expf(-x)); }
static __device__ __forceinline__ float tanhfast(float x)  { return 2.f / (1.f + __expf(-2.f * x)) - 1.f; }

// ---------------------------------------------------------------------------
// prep: (a) lstm W frags (r0 layout); (b) lin/ul B-frags; (c) lengths/paths
// ---------------------------------------------------------------------------
__global__ void prep_kernel(
    const float* __restrict__ tWif, const float* __restrict__ tWhf,
    const float* __restrict__ tWib, const float* __restrict__ tWhb,
    const float* __restrict__ pWif, const float* __restrict__ pWhf,
    const float* __restrict__ pWib, const float* __restrict__ pWhb,
    const float* __restrict__ linW, const float* __restrict__ ulW,
    const int* __restrict__ units, const int* __restrict__ paths,
    const int* __restrict__ upd, const int* __restrict__ ppd,
    float* __restrict__ ws, int* __restrict__ ip)
{
  int idx = blockIdx.x * 256 + threadIdx.x;
  if (idx < 524288) {
    unsigned short* wf = (unsigned short*)(ws + OFF_WFRAG);
    int mat = idx >> 17, rem = idx & 131071;
    int i  = rem & 7;
    int lane = (rem >> 3) & 63;
    int ct = (rem >> 9) & 3;
    int ks = (rem >> 11) & 7;
    int wv = (rem >> 14) & 7;
    int g = wv * 64 + ct * 16 + (lane & 15);
    int k = ks * 32 + ((lane >> 4) << 3) + i;
    const float* Wi; const float* Wh;
    switch (mat) {
      case 0: Wi = tWif; Wh = tWhf; break;
      case 1: Wi = tWib; Wh = tWhb; break;
      case 2: Wi = pWif; Wh = pWhf; break;
      default: Wi = pWib; Wh = pWhb; break;
    }
    float v = (k < 128) ? Wi[g * 128 + k] : Wh[g * 128 + (k - 128)];
    wf[idx] = f2bf(v);
  } else if (idx < 524288 + 65536) {
    unsigned short* lf = (unsigned short*)(ws + OFF_LINFRAG);
    int i2 = idx - 524288;
    int mat = i2 >> 15, rem = i2 & 32767;
    int i  = rem & 7;
    int lane = (rem >> 3) & 63;
    int ks = (rem >> 9) & 7;
    int ct = (rem >> 12) & 7;
    int e = ct * 16 + (lane & 15);
    int k = ks * 32 + ((lane >> 4) << 3) + i;
    const float* W = mat ? ulW : linW;
    lf[i2] = f2bf(W[e * 256 + k]);
  } else if (idx < 589824 + 4096) {
    int n = idx - 589824;
    int len = T_TOKN;
    for (int t = 0; t < T_TOKN; ++t)
      if (units[t * NUNITS + n] == 0) { len = t; break; }
    ip[n] = len;                                   // tok_len
  } else if (idx < 589824 + 5120) {
    int p = idx - (589824 + 4096);
    int* fe_a  = ip + 4096;
    int* p_len = ip + 5120;
    int* off_p = ip + 6144;
    int* un_p  = ip + 7168;
    int cum = 0; int d = BNUM - 1;
    for (int dd = 0; dd < BNUM; ++dd) {
      int c2 = cum + ppd[dd];
      if (p < c2) { d = dd; break; }
      cum = c2;
    }
    int off = 0;
    for (int dd = 0; dd < d; ++dd) off += upd[dd];
    int un = upd[d];
    off_p[p] = off; un_p[p] = un;
    int f = LPATH;
    for (int t = 0; t < LPATH; ++t)
      if (paths[t * NPATHS + p] == -1) { f = t; break; }
    fe_a[p] = f;
    int pl = LPATH;
    for (int t = 0; t < LPATH; ++t) {
      int v = paths[t * NPATHS + p];
      if ((t >= f) || (v < 0) || (v > un)) { pl = t; break; }
    }
    p_len[p] = pl;
  }
}

// ---------------------------------------------------------------------------
// MFMA BiLSTM, 16-wave blocks, resident B (32 gate-cols/wave, 64 VGPR/lane).
// Base = round-0 structure (best measured: 87.8us/dispatch). Round-4 deltas,
// all targeting exposed latency at the per-phase vmcnt(0)+barrier drains:
//  (1) idx columns preloaded to LDS once -> in-loop gather is a single
//      global load issued at MFMA-phase start, consumed next phase.
//  (2) h global store DEFERRED one phase (hp kept in regs): issued at the
//      next MFMA-phase start, so its drain hides under the whole phase.
//  (3) wave-uniform dead-step skip of the transcendental chain (mean len
//      ~0.63*TT); dead positions store 0 (finite -> masked downstream).
// MODE 0: token (emb gather, M=32, thread = 2 units x 2 cols).
// MODE 1: path (tok_feat gather w/ keep mask, M=8, scalar pointwise).
// ---------------------------------------------------------------------------
template <int MODE>
__global__ __launch_bounds__(1024, 4) void lstm_kernel(
    const unsigned short* __restrict__ wfragAll,
    const float* __restrict__ biasF, const float* __restrict__ biasB,
    const float* __restrict__ src,       // emb or tok_feat (f32)
    const int* __restrict__ idxsrc,      // units or paths
    const int* __restrict__ lens,        // tok_len or p_len
    const int* __restrict__ fe_a, const int* __restrict__ off_p, const int* __restrict__ un_p,
    unsigned short* __restrict__ outF, unsigned short* __restrict__ outB)
{
  constexpr int NN   = MODE ? NPATHS : NUNITS;
  constexpr int TT   = MODE ? LPATH : T_TOKN;
  constexpr int M    = MODE ? 8 : 32;     // real sequences per block
  constexpr int MR   = MODE ? 16 : 32;    // MFMA tile rows
  constexpr int NRT  = MR / 16;
  constexpr int ASTR = 264;               // A-tile row stride (ushorts)
  constexpr int GSTR = 514;               // gates row stride (f32)

  __shared__ unsigned short ash[MR * ASTR];  // [u][0:128)=x  [u][128:256)=h
  __shared__ float gates[MR * GSTR];
  __shared__ int   idxL[M * TT];             // preloaded index columns

  int tid  = threadIdx.x;
  int dir  = blockIdx.y;
  int n0   = blockIdx.x * M;
  int lane = tid & 63, wv = tid >> 6;       // wv in [0,16)

  // ---- resident B fragments: wave wv covers gates [wv*32, wv*32+32) ----
  const unsigned short* wbase =
      wfragAll + (size_t)((MODE ? 2 : 0) + dir) * 131072;
  int wv8 = wv >> 1;
  short8 bfr[8][2];
#pragma unroll
  for (int ks = 0; ks < 8; ++ks)
#pragma unroll
    for (int c2 = 0; c2 < 2; ++c2) {
      int ct = ((wv & 1) << 1) | c2;
      bfr[ks][c2] = *(const short8*)&wbase[((((wv8 * 8 + ks) * 4 + ct) * 64) + lane) * 8];
    }

  // ---- zero LDS (h region; MODE 1: whole tile incl dummy rows) ----
  if (MODE == 0) {
    for (int i = tid; i < MR * 128; i += 1024)
      ash[(i >> 7) * ASTR + 128 + (i & 127)] = 0;
  } else {
    for (int i = tid; i < MR * ASTR; i += 1024) ash[i] = 0;
  }
  // ---- preload idx columns: idxL[u*TT + t] = idxsrc[t*NN + n0+u] ----
  for (int i = tid; i < M * TT; i += 1024) {
    int u = i / TT, tt = i - u * TT;       // TT is power of two -> shifts
    idxL[i] = idxsrc[tt * NN + (n0 + u)];
  }

  // ---- pointwise thread state ----
  const float* bcp = dir ? biasB : biasF;
  // MODE 0: thread = wave's unit pair x j pair.  MODE 1: 1 unit x 1 j.
  int j2 = MODE ? (tid & 127) : ((tid & 63) * 2);
  int ug = MODE ? (tid >> 7)  : (tid >> 6);
  float2 b2[4];
#pragma unroll
  for (int q = 0; q < 4; ++q) {
    if (MODE == 0) b2[q] = *(const float2*)&bcp[q * 128 + j2];
    else           b2[q] = make_float2(bcp[q * 128 + j2], 0.f);
  }
  constexpr int NU = MODE ? 1 : 2;          // units per pointwise thread
  float cst0[NU], cst1[NU];
  int   ulen[NU];
  unsigned hp_prev[NU];
#pragma unroll
  for (int i = 0; i < NU; ++i) {
    cst0[i] = 0.f; cst1[i] = 0.f;
    ulen[i] = lens[n0 + ug * NU + i];
    hp_prev[i] = 0u;
  }

  // ---- gather thread state ----
  int gu, gk0;
  if (MODE == 0) { gu = tid >> 5; gk0 = (tid & 31) * 4; }   // 32 rows x 32 thr
  else           { gu = tid >> 7; gk0 = tid & 127; }        // 8 rows x 128 thr
  int gn = n0 + gu;
  int glen = lens[gn];
  int gfe = 0, goff = 0, gun = 0;
  if (MODE) { gfe = fe_a[gn]; goff = off_p[gn]; gun = un_p[gn]; }

  float4 xq; float xs;
  __syncthreads();   // zeros + idxL visible

  // ---- preamble: load + write x(0) ----
  {
    int tau = dir ? min(max(glen - 1, 0), TT - 1) : 0;
    int v = idxL[gu * TT + tau];
    if (MODE == 0) {
      xq = *(const float4*)&src[(size_t)v * 128 + gk0];
    } else {
      bool keep = (tau < gfe) && (v >= 0) && (v < gun);
      xs = keep ? src[(size_t)min(v + goff, NUNITS - 1) * 128 + gk0] : 0.f;
    }
  }
  if (MODE == 0) {
    short4x x4;
    x4[0] = (short)f2bf(xq.x); x4[1] = (short)f2bf(xq.y);
    x4[2] = (short)f2bf(xq.z); x4[3] = (short)f2bf(xq.w);
    *(short4x*)&ash[gu * ASTR + gk0] = x4;
  } else {
    ash[gu * ASTR + gk0] = f2bf(xs);
  }
  __syncthreads();   // x(0) visible

#pragma unroll 1
  for (int t = 0; t < TT; ++t) {
    // ===== MFMA phase =====
    // (a) deferred global store of h(t-1) — drains under this phase
    if (t > 0) {
      int tpw = t - 1;
#pragma unroll
      for (int i = 0; i < NU; ++i) {
        int u = ug * NU + i, n = n0 + u, L = ulen[i];
        bool vld = tpw < L;
        if (MODE == 0) {
          if (dir == 0) {
            *(unsigned*)&outF[((size_t)tpw * NN + n) * 128 + j2] = hp_prev[i];
          } else {
            size_t tr = vld ? (size_t)(L - 1 - tpw) : (size_t)tpw;
            *(unsigned*)&outB[(tr * NN + n) * 128 + j2] = vld ? hp_prev[i] : 0u;
          }
        } else {
          unsigned short hb = (unsigned short)hp_prev[i];
          if (dir == 0) {
            outF[((size_t)tpw * NN + n) * 128 + j2] = hb;
          } else {
            size_t tr = vld ? (size_t)(L - 1 - tpw) : (size_t)tpw;
            outB[(tr * NN + n) * 128 + j2] = vld ? hb : (unsigned short)0;
          }
        }
      }
    }
    // (b) prefetch x(t+1): idx from LDS -> single global load, spans phase
    {
      int tn = (t + 1 < TT) ? t + 1 : t;
      int taun = dir ? min(max(glen - 1 - tn, 0), TT - 1) : tn;
      int vn = idxL[gu * TT + taun];
      if (MODE == 0) {
        xq = *(const float4*)&src[(size_t)vn * 128 + gk0];
      } else {
        bool keep = (taun < gfe) && (vn >= 0) && (vn < gun);
        xs = keep ? src[(size_t)min(vn + goff, NUNITS - 1) * 128 + gk0] : 0.f;
      }
    }
    // (c) MFMA gate GEMM (K=256, resident B)
    {
      f32x4 acc[NRT][2];
#pragma unroll
      for (int rt = 0; rt < NRT; ++rt)
#pragma unroll
        for (int c2 = 0; c2 < 2; ++c2) {
          f32x4 z = {0.f, 0.f, 0.f, 0.f};
          acc[rt][c2] = z;
        }
#pragma unroll
      for (int ks = 0; ks < 8; ++ks) {
        short8 afr[NRT];
#pragma unroll
        for (int rt = 0; rt < NRT; ++rt)
          afr[rt] = *(const short8*)&ash[(rt * 16 + (lane & 15)) * ASTR + ks * 32 + ((lane >> 4) << 3)];
#pragma unroll
        for (int rt = 0; rt < NRT; ++rt)
#pragma unroll
          for (int c2 = 0; c2 < 2; ++c2)
            acc[rt][c2] = __builtin_amdgcn_mfma_f32_16x16x32_bf16(
                afr[rt], bfr[ks][c2], acc[rt][c2], 0, 0, 0);
      }
      // preacts -> LDS gates (C-layout: col=lane&15, row=quad*4+reg)
#pragma unroll
      for (int rt = 0; rt < NRT; ++rt)
#pragma unroll
        for (int c2 = 0; c2 < 2; ++c2) {
          int g = wv * 32 + c2 * 16 + (lane & 15);
#pragma unroll
          for (int r = 0; r < 4; ++r) {
            int u = rt * 16 + ((lane >> 4) << 2) + r;
            gates[u * GSTR + g] = acc[rt][c2][r];
          }
        }
    }
    __syncthreads();   // gates ready; A-tile reads done

    // ===== PW phase =====
#pragma unroll
    for (int i = 0; i < NU; ++i) {
      int u = ug * NU + i;
      int L = ulen[i];
      if (t < L) {   // wave-uniform: skip transcendentals on dead steps
        if (MODE == 0) {
          float2 g0 = *(const float2*)&gates[u * GSTR + j2];
          float2 g1 = *(const float2*)&gates[u * GSTR + 128 + j2];
          float2 g2 = *(const float2*)&gates[u * GSTR + 256 + j2];
          float2 g3 = *(const float2*)&gates[u * GSTR + 384 + j2];
          float i0 = sigf(g0.x + b2[0].x), i1 = sigf(g0.y + b2[0].y);
          float f0 = sigf(g1.x + b2[1].x), f1 = sigf(g1.y + b2[1].y);
          float c0 = tanhfast(g2.x + b2[2].x), c1 = tanhfast(g2.y + b2[2].y);
          float o0 = sigf(g3.x + b2[3].x), o1 = sigf(g3.y + b2[3].y);
          float cA = f0 * cst0[i] + i0 * c0;
          float cB = f1 * cst1[i] + i1 * c1;
          cst0[i] = cA; cst1[i] = cB;
          unsigned hp = pack_bf(o0 * tanhfast(cA), o1 * tanhfast(cB));
          *(unsigned*)&ash[u * ASTR + 128 + j2] = hp;
          hp_prev[i] = hp;
        } else {
          float p0 = gates[u * GSTR + j2]       + b2[0].x;
          float p1 = gates[u * GSTR + 128 + j2] + b2[1].x;
          float p2 = gates[u * GSTR + 256 + j2] + b2[2].x;
          float p3 = gates[u * GSTR + 384 + j2] + b2[3].x;
          float ig = sigf(p0), fg = sigf(p1), gg = tanhfast(p2), og = sigf(p3);
          float c = fg * cst0[i] + ig * gg;
          cst0[i] = c;
          unsigned short hb = f2bf(og * tanhfast(c));
          ash[u * ASTR + 128 + j2] = hb;
          hp_prev[i] = (unsigned)hb;
        }
      } else {
        hp_prev[i] = 0u;   // dead step: finite zero stored next phase
      }
    }
    // x(t+1) into A-tile (prefetch from MFMA phase; vm wait ~a full phase old)
    if (t + 1 < TT) {
      if (MODE == 0) {
        short4x x4;
        x4[0] = (short)f2bf(xq.x); x4[1] = (short)f2bf(xq.y);
        x4[2] = (short)f2bf(xq.z); x4[3] = (short)f2bf(xq.w);
        *(short4x*)&ash[gu * ASTR + gk0] = x4;
      } else {
        ash[gu * ASTR + gk0] = f2bf(xs);
      }
    }
    __syncthreads();   // h(t) + x(t+1) visible
  }

  // ===== epilogue: store h(TT-1) =====
  {
    int tpw = TT - 1;
#pragma unroll
    for (int i = 0; i < NU; ++i) {
      int u = ug * NU + i, n = n0 + u, L = ulen[i];
      bool vld = tpw < L;
      if (MODE == 0) {
        if (dir == 0) {
          *(unsigned*)&outF[((size_t)tpw * NN + n) * 128 + j2] = hp_prev[i];
        } else {
          size_t tr = vld ? (size_t)(L - 1 - tpw) : (size_t)tpw;
          *(unsigned*)&outB[(tr * NN + n) * 128 + j2] = vld ? hp_prev[i] : 0u;
        }
      } else {
        unsigned short hb = (unsigned short)hp_prev[i];
        if (dir == 0) {
          outF[((size_t)tpw * NN + n) * 128 + j2] = hb;
        } else {
          size_t tr = vld ? (size_t)(L - 1 - tpw) : (size_t)tpw;
          outB[(tr * NN + n) * 128 + j2] = vld ? hb : (unsigned short)0;
        }
      }
    }
  }
}

// ---------------------------------------------------------------------------
// MFMA GEMM: rows x 128, K=256, A = bf16 [INf|INb] from global, B resident
// (64 VGPR/lane, 4 waves cover 128 cols).  C+bias -> LDS tile -> epilogue.
// EPI 0: row-validity mask on A (invalid rows -> OUT = bias), f32 store.
// EPI 1: store OUT + fused LayerNorm+tanh+attention scores.
// ---------------------------------------------------------------------------
template <int EPI>
__global__ __launch_bounds__(256) void gemm_mfma(
    const unsigned short* __restrict__ INf, const unsigned short* __restrict__ INb,
    const int* __restrict__ lens,
    const unsigned short* __restrict__ Bfrag, const float* __restrict__ bias,
    float* __restrict__ OUT, float* __restrict__ scores,
    const float* __restrict__ lng, const float* __restrict__ lnb,
    const float* __restrict__ attw, const float* __restrict__ attb,
    const int* __restrict__ units, int Nn)
{
  constexpr int OSTR = 132;
  __shared__ float outs[64 * OSTR];
  __shared__ float red1[256];
  __shared__ float red2[256];
  __shared__ float rowm[64], rowr[64];
  __shared__ float awsh[128], lgsh[128], lbsh[128];

  int tid = threadIdx.x, lane = tid & 63, wv = tid >> 6;
  int row0 = blockIdx.x * 64;
  int t = row0 / Nn, n0 = row0 % Nn;   // 64-row blocks never straddle t

  if (EPI == 1 && tid < 128) {
    awsh[tid] = attw[tid]; lgsh[tid] = lng[tid]; lbsh[tid] = lnb[tid];
  }

  short8 bfr[8][2];
#pragma unroll
  for (int ks = 0; ks < 8; ++ks)
#pragma unroll
    for (int c2 = 0; c2 < 2; ++c2) {
      int ct = wv * 2 + c2;
      bfr[ks][c2] = *(const short8*)&Bfrag[(((ct * 8 + ks) * 64) + lane) * 8];
    }

  int rb = lane & 15;
  int koq = (lane >> 4) << 3;
  bool val[4];
#pragma unroll
  for (int rt = 0; rt < 4; ++rt)
    val[rt] = (EPI == 1) ? true : (t < lens[n0 + rt * 16 + rb]);

  f32x4 acc[4][2];
#pragma unroll
  for (int rt = 0; rt < 4; ++rt)
#pragma unroll
    for (int c2 = 0; c2 < 2; ++c2) {
      f32x4 z = {0.f, 0.f, 0.f, 0.f};
      acc[rt][c2] = z;
    }

#pragma unroll
  for (int ks = 0; ks < 8; ++ks) {
    const unsigned short* P = (ks < 4) ? INf : INb;
    int koff = (ks & 3) * 32 + koq;
#pragma unroll
    for (int rt = 0; rt < 4; ++rt) {
      short8 a = {0, 0, 0, 0, 0, 0, 0, 0};
      if (val[rt])
        a = *(const short8*)&P[((size_t)(row0 + rt * 16 + rb)) * 128 + koff];
#pragma unroll
      for (int c2 = 0; c2 < 2; ++c2)
        acc[rt][c2] = __builtin_amdgcn_mfma_f32_16x16x32_bf16(
            a, bfr[ks][c2], acc[rt][c2], 0, 0, 0);
    }
  }

  float bc[2];
#pragma unroll
  for (int c2 = 0; c2 < 2; ++c2) bc[c2] = bias[wv * 32 + c2 * 16 + rb];
#pragma unroll
  for (int rt = 0; rt < 4; ++rt)
#pragma unroll
    for (int c2 = 0; c2 < 2; ++c2) {
      int col = wv * 32 + c2 * 16 + rb;
      int ub  = rt * 16 + ((lane >> 4) << 2);
#pragma unroll
      for (int r = 0; r < 4; ++r)
        outs[(ub + r) * OSTR + col] = acc[rt][c2][r] + bc[c2];
    }
  __syncthreads();

  int row = tid >> 2, seg = tid & 3;
  const float* rp = &outs[row * OSTR + seg * 32];
  size_t go = ((size_t)(row0 + row)) * 128 + seg * 32;

  if (EPI == 0) {
#pragma unroll
    for (int x = 0; x < 8; ++x)
      *(f32x4*)&OUT[go + x * 4] = *(const f32x4*)&rp[x * 4];
  } else {
    f32x4 v[8];
    float s = 0.f, s2 = 0.f;
#pragma unroll
    for (int x = 0; x < 8; ++x) {
      v[x] = *(const f32x4*)&rp[x * 4];
#pragma unroll
      for (int c = 0; c < 4; ++c) { s += v[x][c]; s2 += v[x][c] * v[x][c]; }
    }
    red1[tid] = s; red2[tid] = s2;
    __syncthreads();
    if (tid < 64) {
      float a = red1[tid * 4] + red1[tid * 4 + 1] + red1[tid * 4 + 2] + red1[tid * 4 + 3];
      float b = red2[tid * 4] + red2[tid * 4 + 1] + red2[tid * 4 + 2] + red2[tid * 4 + 3];
      float m = a * (1.f / 128.f);
      float var = b * (1.f / 128.f) - m * m;
      rowm[tid] = m;
      rowr[tid] = rsqrtf(var + 1e-5f);
    }
    __syncthreads();
    float m = rowm[row], rs = rowr[row];
    float sp = 0.f;
#pragma unroll
    for (int x = 0; x < 8; ++x) {
#pragma unroll
      for (int c = 0; c < 4; ++c) {
        int col = seg * 32 + x * 4 + c;
        float q = tanhfast((v[x][c] - m) * rs * lgsh[col] + lbsh[col]);
        sp += q * awsh[col];
      }
      *(f32x4*)&OUT[go + x * 4] = v[x];
    }
    red1[tid] = sp;
    __syncthreads();
    if (tid < 64) {
      float s3 = red1[tid * 4] + red1[tid * 4 + 1] + red1[tid * 4 + 2] + red1[tid * 4 + 3]
               + attb[0];
      int n = n0 + tid;
      if (units[t * NUNITS + n] == 0) s3 = -1e9f;
      scores[t * NUNITS + n] = s3;
    }
  }
}

// ---------------------------------------------------------------------------
// Softmax over T=16 + attention-weighted pooling -> tok_feat[n][e]
// ---------------------------------------------------------------------------
__global__ __launch_bounds__(128) void softmax_feat_kernel(
    const float* __restrict__ scores, const float* __restrict__ out_lin,
    float* __restrict__ tok_feat)
{
  int n = blockIdx.x;
  int e = threadIdx.x;
  float s[T_TOKN];
  float m = -1e30f;
#pragma unroll
  for (int t = 0; t < T_TOKN; ++t) { s[t] = scores[t * NUNITS + n]; m = fmaxf(m, s[t]); }
  float sum = 0.f;
#pragma unroll
  for (int t = 0; t < T_TOKN; ++t) { s[t] = expf(s[t] - m); sum += s[t]; }
  float inv = 1.f / sum;
  float a = 0.f;
#pragma unroll
  for (int t = 0; t < T_TOKN; ++t)
    a += s[t] * inv * out_lin[((size_t)t * NUNITS + n) * 128 + e];
  tok_feat[n * 128 + e] = a;
}

// ---------------------------------------------------------------------------
extern "C" void kernel_launch(void* const* d_in, const int* in_sizes, int n_in,
                              void* d_out, int out_size, void* d_ws, size_t ws_size,
                              hipStream_t stream)
{
  const int*   units = (const int*)d_in[0];
  const int*   paths = (const int*)d_in[1];
  const int*   upd   = (const int*)d_in[2];
  const int*   ppd   = (const int*)d_in[3];
  const float* emb   = (const float*)d_in[4];
  const float* tWif  = (const float*)d_in[5];
  const float* tWhf  = (const float*)d_in[6];
  const float* tbf   = (const float*)d_in[7];
  const float* tWib  = (const float*)d_in[8];
  const float* tWhb  = (const float*)d_in[9];
  const float* tbb   = (const float*)d_in[10];
  const float* linW  = (const float*)d_in[11];
  const float* linb  = (const float*)d_in[12];
  const float* lng   = (const float*)d_in[13];
  const float* lnb   = (const float*)d_in[14];
  const float* attw  = (const float*)d_in[15];
  const float* attb  = (const float*)d_in[16];
  const float* pWif  = (const float*)d_in[17];
  const float* pWhf  = (const float*)d_in[18];
  const float* pbf   = (const float*)d_in[19];
  const float* pWib  = (const float*)d_in[20];
  const float* pWhb  = (const float*)d_in[21];
  const float* pbb   = (const float*)d_in[22];
  const float* ulW   = (const float*)d_in[23];
  const float* ulb   = (const float*)d_in[24];

  float* ws = (float*)d_ws;
  int*   ip = (int*)(ws + OFF_INT);
  if (ws_size < WS_FLOATS * sizeof(float)) return;

  unsigned short* wfrag   = (unsigned short*)(ws + OFF_WFRAG);
  unsigned short* linfrag = (unsigned short*)(ws + OFF_LINFRAG);
  unsigned short* ulfrag  = linfrag + 32768;
  unsigned short* OUTF  = (unsigned short*)(ws + OFF_OUTF);
  unsigned short* OUTB  = (unsigned short*)(ws + OFF_OUTB);
  unsigned short* POUTF = (unsigned short*)(ws + OFF_POUTF);
  unsigned short* POUTB = (unsigned short*)(ws + OFF_POUTB);

  prep_kernel<<<2324, 256, 0, stream>>>(tWif, tWhf, tWib, tWhb,
                                        pWif, pWhf, pWib, pWhb,
                                        linW, ulW, units, paths, upd, ppd,
                                        ws, ip);

  lstm_kernel<0><<<dim3(128, 2), 1024, 0, stream>>>(
      wfrag, tbf, tbb, emb, units, ip /*tok_len*/, nullptr, nullptr, nullptr,
      OUTF, OUTB);

  gemm_mfma<1><<<1024, 256, 0, stream>>>(
      OUTF, OUTB, ip /*tok_len*/, linfrag, linb,
      ws + OFF_OUTLIN, ws + OFF_SCORES, lng, lnb, attw, attb, units, NUNITS);

  softmax_feat_kernel<<<4096, 128, 0, stream>>>(ws + OFF_SCORES, ws + OFF_OUTLIN,
                                                ws + OFF_TOKFEAT);

  lstm_kernel<1><<<dim3(128, 2), 1024, 0, stream>>>(
      wfrag, pbf, pbb, ws + OFF_TOKFEAT, paths, ip + 5120 /*p_len*/,
      ip + 4096 /*fe*/, ip + 6144 /*off_p*/, ip + 7168 /*un_p*/,
      POUTF, POUTB);

  gemm_mfma<0><<<512, 256, 0, stream>>>(
      POUTF, POUTB, ip + 5120 /*p_len*/, ulfrag, ulb,
      (float*)d_out, nullptr, nullptr, nullptr, nullptr, nullptr, nullptr, NPATHS);
}

// Round 5
// 306.197 us; speedup vs baseline: 1.3195x; 1.0375x over previous
//
#include <hip/hip_runtime.h>
#include <cstdint>
#include <cstddef>

// Problem constants
#define T_TOKN 16
#define NUNITS 4096
#define LPATH  32
#define NPATHS 1024
#define BNUM   8

typedef __attribute__((ext_vector_type(8))) short short8;   // 8 bf16 in 4 VGPRs
typedef __attribute__((ext_vector_type(4))) short short4x;  // 4 bf16 in 2 VGPRs
typedef __attribute__((ext_vector_type(4))) float f32x4;    // MFMA accumulator

// ws float offsets
enum : size_t {
  OFF_WFRAG   = 0,                        // 524288 ushort: lstm W frags [tf|tb|pf|pb]
  OFF_LINFRAG = 262144,                   // 65536 ushort: lin/ul B-frags
  OFF_OUTF    = 294912,                   // token fwd h, bf16 16x4096x128
  OFF_OUTB    = OFF_OUTF + 4194304,       // token bwd h (time-realigned), bf16
  OFF_OUTLIN  = OFF_OUTB + 4194304,       // bf16 16x4096x128 (intermediate only)
  OFF_SCORES  = OFF_OUTLIN + 8388608,     // f32 16x4096
  OFF_TOKFEAT = OFF_SCORES + 65536,       // f32 4096x128
  OFF_POUTF   = OFF_TOKFEAT + 524288,     // path fwd h, bf16 32x1024x128
  OFF_POUTB   = OFF_POUTF + 2097152,
  OFF_INT     = OFF_POUTB + 2097152,      // ints: tok_len 4096 | fe 1024 | p_len 1024 | off_p 1024 | un_p 1024
  WS_FLOATS   = OFF_INT + 8192
};

static __device__ __forceinline__ unsigned short f2bf(float f) {
  union { float f; unsigned u; } v; v.f = f;
  unsigned r = v.u + 0x7fffu + ((v.u >> 16) & 1u);
  return (unsigned short)(r >> 16);
}
static __device__ __forceinline__ float bf2f(unsigned short u) {
  union { unsigned u; float f; } v; v.u = ((unsigned)u) << 16;
  return v.f;
}
static __device__ __forceinline__ unsigned pack_bf(float a, float b) {
  return (unsigned)f2bf(a) | ((unsigned)f2bf(b) << 16);
}
static __device__ __forceinline__ float sigf(float x)      { return 1.f / (1.f + __expf(-x)); }
static __device__ __forceinline__ float tanhfast(float x)  { return 2.f / (1.f + __expf(-2.f * x)) - 1.f; }

// ---------------------------------------------------------------------------
// prep: (a) lstm W frags (r0 layout); (b) lin/ul B-frags; (c) lengths/paths
// ---------------------------------------------------------------------------
__global__ void prep_kernel(
    const float* __restrict__ tWif, const float* __restrict__ tWhf,
    const float* __restrict__ tWib, const float* __restrict__ tWhb,
    const float* __restrict__ pWif, const float* __restrict__ pWhf,
    const float* __restrict__ pWib, const float* __restrict__ pWhb,
    const float* __restrict__ linW, const float* __restrict__ ulW,
    const int* __restrict__ units, const int* __restrict__ paths,
    const int* __restrict__ upd, const int* __restrict__ ppd,
    float* __restrict__ ws, int* __restrict__ ip)
{
  int idx = blockIdx.x * 256 + threadIdx.x;
  if (idx < 524288) {
    unsigned short* wf = (unsigned short*)(ws + OFF_WFRAG);
    int mat = idx >> 17, rem = idx & 131071;
    int i  = rem & 7;
    int lane = (rem >> 3) & 63;
    int ct = (rem >> 9) & 3;
    int ks = (rem >> 11) & 7;
    int wv = (rem >> 14) & 7;
    int g = wv * 64 + ct * 16 + (lane & 15);
    int k = ks * 32 + ((lane >> 4) << 3) + i;
    const float* Wi; const float* Wh;
    switch (mat) {
      case 0: Wi = tWif; Wh = tWhf; break;
      case 1: Wi = tWib; Wh = tWhb; break;
      case 2: Wi = pWif; Wh = pWhf; break;
      default: Wi = pWib; Wh = pWhb; break;
    }
    float v = (k < 128) ? Wi[g * 128 + k] : Wh[g * 128 + (k - 128)];
    wf[idx] = f2bf(v);
  } else if (idx < 524288 + 65536) {
    unsigned short* lf = (unsigned short*)(ws + OFF_LINFRAG);
    int i2 = idx - 524288;
    int mat = i2 >> 15, rem = i2 & 32767;
    int i  = rem & 7;
    int lane = (rem >> 3) & 63;
    int ks = (rem >> 9) & 7;
    int ct = (rem >> 12) & 7;
    int e = ct * 16 + (lane & 15);
    int k = ks * 32 + ((lane >> 4) << 3) + i;
    const float* W = mat ? ulW : linW;
    lf[i2] = f2bf(W[e * 256 + k]);
  } else if (idx < 589824 + 4096) {
    int n = idx - 589824;
    int len = T_TOKN;
    for (int t = 0; t < T_TOKN; ++t)
      if (units[t * NUNITS + n] == 0) { len = t; break; }
    ip[n] = len;                                   // tok_len
  } else if (idx < 589824 + 5120) {
    int p = idx - (589824 + 4096);
    int* fe_a  = ip + 4096;
    int* p_len = ip + 5120;
    int* off_p = ip + 6144;
    int* un_p  = ip + 7168;
    int cum = 0; int d = BNUM - 1;
    for (int dd = 0; dd < BNUM; ++dd) {
      int c2 = cum + ppd[dd];
      if (p < c2) { d = dd; break; }
      cum = c2;
    }
    int off = 0;
    for (int dd = 0; dd < d; ++dd) off += upd[dd];
    int un = upd[d];
    off_p[p] = off; un_p[p] = un;
    int f = LPATH;
    for (int t = 0; t < LPATH; ++t)
      if (paths[t * NPATHS + p] == -1) { f = t; break; }
    fe_a[p] = f;
    int pl = LPATH;
    for (int t = 0; t < LPATH; ++t) {
      int v = paths[t * NPATHS + p];
      if ((t >= f) || (v < 0) || (v > un)) { pl = t; break; }
    }
    p_len[p] = pl;
  }
}

// ---------------------------------------------------------------------------
// MFMA BiLSTM, 16-wave blocks, resident B (32 gate-cols/wave, 64 VGPR/lane).
// Round-5 = round-0 proven structure + the two r4 deltas that helped:
//  (1) idx columns preloaded to LDS (kills dependent 2-level gather chain;
//      mainly a MODE 1 win).
//  (2) wave-uniform dead-step skip of the transcendental chain (halved
//      VALUBusy in r4); dead positions store 0 (masked downstream: gemm
//      val[] masks t>=len rows, scores masked by units==0 -> softmax w=0).
// r4's deferred-store / phase-start-prefetch reordering is REVERTED (it
// cost +8us and +13MB of traffic on MODE 0): x-prefetch is issued between
// MFMA and gates-store as in r0; h stored directly in the PW phase.
// MODE 0: token (emb gather, M=32, thread = 2 units x 2 cols).
// MODE 1: path (tok_feat gather w/ keep mask, M=8, scalar pointwise).
// ---------------------------------------------------------------------------
template <int MODE>
__global__ __launch_bounds__(1024, 4) void lstm_kernel(
    const unsigned short* __restrict__ wfragAll,
    const float* __restrict__ biasF, const float* __restrict__ biasB,
    const float* __restrict__ src,       // emb or tok_feat (f32)
    const int* __restrict__ idxsrc,      // units or paths
    const int* __restrict__ lens,        // tok_len or p_len
    const int* __restrict__ fe_a, const int* __restrict__ off_p, const int* __restrict__ un_p,
    unsigned short* __restrict__ outF, unsigned short* __restrict__ outB)
{
  constexpr int NN   = MODE ? NPATHS : NUNITS;
  constexpr int TT   = MODE ? LPATH : T_TOKN;
  constexpr int M    = MODE ? 8 : 32;     // real sequences per block
  constexpr int MR   = MODE ? 16 : 32;    // MFMA tile rows
  constexpr int NRT  = MR / 16;
  constexpr int ASTR = 264;               // A-tile row stride (ushorts)
  constexpr int GSTR = 514;               // gates row stride (f32)

  __shared__ unsigned short ash[MR * ASTR];  // [u][0:128)=x  [u][128:256)=h
  __shared__ float gates[MR * GSTR];
  __shared__ int   idxL[M * TT];             // preloaded index columns

  int tid  = threadIdx.x;
  int dir  = blockIdx.y;
  int n0   = blockIdx.x * M;
  int lane = tid & 63, wv = tid >> 6;       // wv in [0,16)

  // ---- resident B fragments: wave wv covers gates [wv*32, wv*32+32) ----
  const unsigned short* wbase =
      wfragAll + (size_t)((MODE ? 2 : 0) + dir) * 131072;
  int wv8 = wv >> 1;
  short8 bfr[8][2];
#pragma unroll
  for (int ks = 0; ks < 8; ++ks)
#pragma unroll
    for (int c2 = 0; c2 < 2; ++c2) {
      int ct = ((wv & 1) << 1) | c2;
      bfr[ks][c2] = *(const short8*)&wbase[((((wv8 * 8 + ks) * 4 + ct) * 64) + lane) * 8];
    }

  // ---- zero LDS (h region; MODE 1: whole tile incl dummy rows) ----
  if (MODE == 0) {
    for (int i = tid; i < MR * 128; i += 1024)
      ash[(i >> 7) * ASTR + 128 + (i & 127)] = 0;
  } else {
    for (int i = tid; i < MR * ASTR; i += 1024) ash[i] = 0;
  }
  // ---- preload idx columns: idxL[u*TT + t] = idxsrc[t*NN + n0+u] ----
  for (int i = tid; i < M * TT; i += 1024) {
    int u = i / TT, tt = i - u * TT;
    idxL[i] = idxsrc[tt * NN + (n0 + u)];
  }

  // ---- pointwise thread state ----
  const float* bcp = dir ? biasB : biasF;
  // MODE 0: thread = wave's unit pair x j pair.  MODE 1: 1 unit x 1 j.
  int j2 = MODE ? (tid & 127) : ((tid & 63) * 2);
  int ug = MODE ? (tid >> 7)  : (tid >> 6);
  float2 b2[4];
#pragma unroll
  for (int q = 0; q < 4; ++q) {
    if (MODE == 0) b2[q] = *(const float2*)&bcp[q * 128 + j2];
    else           b2[q] = make_float2(bcp[q * 128 + j2], 0.f);
  }
  constexpr int NU = MODE ? 1 : 2;          // units per pointwise thread
  float cst0[NU], cst1[NU];
  int   ulen[NU];
#pragma unroll
  for (int i = 0; i < NU; ++i) {
    cst0[i] = 0.f; cst1[i] = 0.f;
    ulen[i] = lens[n0 + ug * NU + i];
  }

  // ---- gather thread state ----
  int gu, gk0;
  if (MODE == 0) { gu = tid >> 5; gk0 = (tid & 31) * 4; }   // 32 rows x 32 thr
  else           { gu = tid >> 7; gk0 = tid & 127; }        // 8 rows x 128 thr
  int gn = n0 + gu;
  int glen = lens[gn];
  int gfe = 0, goff = 0, gun = 0;
  if (MODE) { gfe = fe_a[gn]; goff = off_p[gn]; gun = un_p[gn]; }

  float4 xq; float xs;
  __syncthreads();   // zeros + idxL visible

  // ---- preamble: load + write x(0) ----
  {
    int tau = dir ? min(max(glen - 1, 0), TT - 1) : 0;
    int v = idxL[gu * TT + tau];
    if (MODE == 0) {
      xq = *(const float4*)&src[(size_t)v * 128 + gk0];
    } else {
      bool keep = (tau < gfe) && (v >= 0) && (v < gun);
      xs = keep ? src[(size_t)min(v + goff, NUNITS - 1) * 128 + gk0] : 0.f;
    }
  }
  if (MODE == 0) {
    short4x x4;
    x4[0] = (short)f2bf(xq.x); x4[1] = (short)f2bf(xq.y);
    x4[2] = (short)f2bf(xq.z); x4[3] = (short)f2bf(xq.w);
    *(short4x*)&ash[gu * ASTR + gk0] = x4;
  } else {
    ash[gu * ASTR + gk0] = f2bf(xs);
  }
  __syncthreads();   // x(0) visible

#pragma unroll 1
  for (int t = 0; t < TT; ++t) {
    // ===== MFMA phase (r0 ordering) =====
    {
      int tn = (t + 1 < TT) ? t + 1 : t;
      int taun = dir ? min(max(glen - 1 - tn, 0), TT - 1) : tn;
      int vn = idxL[gu * TT + taun];     // LDS read; no global idx chain
      f32x4 acc[NRT][2];
#pragma unroll
      for (int rt = 0; rt < NRT; ++rt)
#pragma unroll
        for (int c2 = 0; c2 < 2; ++c2) {
          f32x4 z = {0.f, 0.f, 0.f, 0.f};
          acc[rt][c2] = z;
        }
#pragma unroll
      for (int ks = 0; ks < 8; ++ks) {
        short8 afr[NRT];
#pragma unroll
        for (int rt = 0; rt < NRT; ++rt)
          afr[rt] = *(const short8*)&ash[(rt * 16 + (lane & 15)) * ASTR + ks * 32 + ((lane >> 4) << 3)];
#pragma unroll
        for (int rt = 0; rt < NRT; ++rt)
#pragma unroll
          for (int c2 = 0; c2 < 2; ++c2)
            acc[rt][c2] = __builtin_amdgcn_mfma_f32_16x16x32_bf16(
                afr[rt], bfr[ks][c2], acc[rt][c2], 0, 0, 0);
      }
      // dependent x(t+1) load — latency overlaps gates-write + barrier
      if (MODE == 0) {
        xq = *(const float4*)&src[(size_t)vn * 128 + gk0];
      } else {
        bool keep = (taun < gfe) && (vn >= 0) && (vn < gun);
        xs = keep ? src[(size_t)min(vn + goff, NUNITS - 1) * 128 + gk0] : 0.f;
      }
      // preacts -> LDS gates (C-layout: col=lane&15, row=quad*4+reg)
#pragma unroll
      for (int rt = 0; rt < NRT; ++rt)
#pragma unroll
        for (int c2 = 0; c2 < 2; ++c2) {
          int g = wv * 32 + c2 * 16 + (lane & 15);
#pragma unroll
          for (int r = 0; r < 4; ++r) {
            int u = rt * 16 + ((lane >> 4) << 2) + r;
            gates[u * GSTR + g] = acc[rt][c2][r];
          }
        }
    }
    __syncthreads();   // gates ready; A-tile reads done

    // ===== PW phase (direct stores; wave-uniform dead-step skip) =====
#pragma unroll
    for (int i = 0; i < NU; ++i) {
      int u = ug * NU + i;
      int n = n0 + u;
      int L = ulen[i];
      if (t < L) {
        if (MODE == 0) {
          float2 g0 = *(const float2*)&gates[u * GSTR + j2];
          float2 g1 = *(const float2*)&gates[u * GSTR + 128 + j2];
          float2 g2 = *(const float2*)&gates[u * GSTR + 256 + j2];
          float2 g3 = *(const float2*)&gates[u * GSTR + 384 + j2];
          float i0 = sigf(g0.x + b2[0].x), i1 = sigf(g0.y + b2[0].y);
          float f0 = sigf(g1.x + b2[1].x), f1 = sigf(g1.y + b2[1].y);
          float c0 = tanhfast(g2.x + b2[2].x), c1 = tanhfast(g2.y + b2[2].y);
          float o0 = sigf(g3.x + b2[3].x), o1 = sigf(g3.y + b2[3].y);
          float cA = f0 * cst0[i] + i0 * c0;
          float cB = f1 * cst1[i] + i1 * c1;
          cst0[i] = cA; cst1[i] = cB;
          unsigned hp = pack_bf(o0 * tanhfast(cA), o1 * tanhfast(cB));
          *(unsigned*)&ash[u * ASTR + 128 + j2] = hp;
          if (dir == 0) {
            *(unsigned*)&outF[((size_t)t * NN + n) * 128 + j2] = hp;
          } else {
            *(unsigned*)&outB[((size_t)(L - 1 - t) * NN + n) * 128 + j2] = hp;
          }
        } else {
          float p0 = gates[u * GSTR + j2]       + b2[0].x;
          float p1 = gates[u * GSTR + 128 + j2] + b2[1].x;
          float p2 = gates[u * GSTR + 256 + j2] + b2[2].x;
          float p3 = gates[u * GSTR + 384 + j2] + b2[3].x;
          float ig = sigf(p0), fg = sigf(p1), gg = tanhfast(p2), og = sigf(p3);
          float c = fg * cst0[i] + ig * gg;
          cst0[i] = c;
          unsigned short hb = f2bf(og * tanhfast(c));
          ash[u * ASTR + 128 + j2] = hb;
          if (dir == 0) outF[((size_t)t * NN + n) * 128 + j2] = hb;
          else          outB[((size_t)(L - 1 - t) * NN + n) * 128 + j2] = hb;
        }
      } else {
        // dead step: store finite zero (masked downstream); skip transcendentals
        if (MODE == 0) {
          if (dir == 0) *(unsigned*)&outF[((size_t)t * NN + n) * 128 + j2] = 0u;
          else          *(unsigned*)&outB[((size_t)t * NN + n) * 128 + j2] = 0u;
        } else {
          if (dir == 0) outF[((size_t)t * NN + n) * 128 + j2] = 0;
          else          outB[((size_t)t * NN + n) * 128 + j2] = 0;
        }
      }
    }
    // x(t+1) into A-tile (prefetched during MFMA phase)
    if (t + 1 < TT) {
      if (MODE == 0) {
        short4x x4;
        x4[0] = (short)f2bf(xq.x); x4[1] = (short)f2bf(xq.y);
        x4[2] = (short)f2bf(xq.z); x4[3] = (short)f2bf(xq.w);
        *(short4x*)&ash[gu * ASTR + gk0] = x4;
      } else {
        ash[gu * ASTR + gk0] = f2bf(xs);
      }
    }
    __syncthreads();   // h(t) + x(t+1) visible
  }
}

// ---------------------------------------------------------------------------
// MFMA GEMM: rows x 128, K=256, A = bf16 [INf|INb] from global, B resident
// (64 VGPR/lane, 4 waves cover 128 cols).  C+bias -> LDS tile -> epilogue.
// EPI 0: row-validity mask on A (invalid rows -> OUT = bias), f32 store.
// EPI 1: store OUT as BF16 (intermediate: softmax-only consumer) + fused
//        LayerNorm+tanh+attention scores.
// ---------------------------------------------------------------------------
template <int EPI>
__global__ __launch_bounds__(256) void gemm_mfma(
    const unsigned short* __restrict__ INf, const unsigned short* __restrict__ INb,
    const int* __restrict__ lens,
    const unsigned short* __restrict__ Bfrag, const float* __restrict__ bias,
    void* __restrict__ OUTv, float* __restrict__ scores,
    const float* __restrict__ lng, const float* __restrict__ lnb,
    const float* __restrict__ attw, const float* __restrict__ attb,
    const int* __restrict__ units, int Nn)
{
  constexpr int OSTR = 132;
  __shared__ float outs[64 * OSTR];
  __shared__ float red1[256];
  __shared__ float red2[256];
  __shared__ float rowm[64], rowr[64];
  __shared__ float awsh[128], lgsh[128], lbsh[128];

  int tid = threadIdx.x, lane = tid & 63, wv = tid >> 6;
  int row0 = blockIdx.x * 64;
  int t = row0 / Nn, n0 = row0 % Nn;   // 64-row blocks never straddle t

  if (EPI == 1 && tid < 128) {
    awsh[tid] = attw[tid]; lgsh[tid] = lng[tid]; lbsh[tid] = lnb[tid];
  }

  short8 bfr[8][2];
#pragma unroll
  for (int ks = 0; ks < 8; ++ks)
#pragma unroll
    for (int c2 = 0; c2 < 2; ++c2) {
      int ct = wv * 2 + c2;
      bfr[ks][c2] = *(const short8*)&Bfrag[(((ct * 8 + ks) * 64) + lane) * 8];
    }

  int rb = lane & 15;
  int koq = (lane >> 4) << 3;
  bool val[4];
#pragma unroll
  for (int rt = 0; rt < 4; ++rt)
    val[rt] = (EPI == 1) ? true : (t < lens[n0 + rt * 16 + rb]);

  f32x4 acc[4][2];
#pragma unroll
  for (int rt = 0; rt < 4; ++rt)
#pragma unroll
    for (int c2 = 0; c2 < 2; ++c2) {
      f32x4 z = {0.f, 0.f, 0.f, 0.f};
      acc[rt][c2] = z;
    }

#pragma unroll
  for (int ks = 0; ks < 8; ++ks) {
    const unsigned short* P = (ks < 4) ? INf : INb;
    int koff = (ks & 3) * 32 + koq;
#pragma unroll
    for (int rt = 0; rt < 4; ++rt) {
      short8 a = {0, 0, 0, 0, 0, 0, 0, 0};
      if (val[rt])
        a = *(const short8*)&P[((size_t)(row0 + rt * 16 + rb)) * 128 + koff];
#pragma unroll
      for (int c2 = 0; c2 < 2; ++c2)
        acc[rt][c2] = __builtin_amdgcn_mfma_f32_16x16x32_bf16(
            a, bfr[ks][c2], acc[rt][c2], 0, 0, 0);
    }
  }

  float bc[2];
#pragma unroll
  for (int c2 = 0; c2 < 2; ++c2) bc[c2] = bias[wv * 32 + c2 * 16 + rb];
#pragma unroll
  for (int rt = 0; rt < 4; ++rt)
#pragma unroll
    for (int c2 = 0; c2 < 2; ++c2) {
      int col = wv * 32 + c2 * 16 + rb;
      int ub  = rt * 16 + ((lane >> 4) << 2);
#pragma unroll
      for (int r = 0; r < 4; ++r)
        outs[(ub + r) * OSTR + col] = acc[rt][c2][r] + bc[c2];
    }
  __syncthreads();

  int row = tid >> 2, seg = tid & 3;
  const float* rp = &outs[row * OSTR + seg * 32];
  size_t go = ((size_t)(row0 + row)) * 128 + seg * 32;

  if (EPI == 0) {
    float* OUT = (float*)OUTv;
#pragma unroll
    for (int x = 0; x < 8; ++x)
      *(f32x4*)&OUT[go + x * 4] = *(const f32x4*)&rp[x * 4];
  } else {
    unsigned short* OUT = (unsigned short*)OUTv;
    f32x4 v[8];
    float s = 0.f, s2 = 0.f;
#pragma unroll
    for (int x = 0; x < 8; ++x) {
      v[x] = *(const f32x4*)&rp[x * 4];
#pragma unroll
      for (int c = 0; c < 4; ++c) { s += v[x][c]; s2 += v[x][c] * v[x][c]; }
    }
    red1[tid] = s; red2[tid] = s2;
    __syncthreads();
    if (tid < 64) {
      float a = red1[tid * 4] + red1[tid * 4 + 1] + red1[tid * 4 + 2] + red1[tid * 4 + 3];
      float b = red2[tid * 4] + red2[tid * 4 + 1] + red2[tid * 4 + 2] + red2[tid * 4 + 3];
      float m = a * (1.f / 128.f);
      float var = b * (1.f / 128.f) - m * m;
      rowm[tid] = m;
      rowr[tid] = rsqrtf(var + 1e-5f);
    }
    __syncthreads();
    float m = rowm[row], rs = rowr[row];
    float sp = 0.f;
#pragma unroll
    for (int x = 0; x < 8; ++x) {
      short4x pv;
#pragma unroll
      for (int c = 0; c < 4; ++c) {
        int col = seg * 32 + x * 4 + c;
        float q = tanhfast((v[x][c] - m) * rs * lgsh[col] + lbsh[col]);
        sp += q * awsh[col];
        pv[c] = (short)f2bf(v[x][c]);
      }
      *(short4x*)&OUT[go + x * 4] = pv;   // bf16 intermediate (8B store)
    }
    red1[tid] = sp;
    __syncthreads();
    if (tid < 64) {
      float s3 = red1[tid * 4] + red1[tid * 4 + 1] + red1[tid * 4 + 2] + red1[tid * 4 + 3]
               + attb[0];
      int n = n0 + tid;
      if (units[t * NUNITS + n] == 0) s3 = -1e9f;
      scores[t * NUNITS + n] = s3;
    }
  }
}

// ---------------------------------------------------------------------------
// Softmax over T=16 + attention-weighted pooling -> tok_feat[n][e]
// out_lin is bf16 now (halved fetch).
// ---------------------------------------------------------------------------
__global__ __launch_bounds__(128) void softmax_feat_kernel(
    const float* __restrict__ scores, const unsigned short* __restrict__ out_lin,
    float* __restrict__ tok_feat)
{
  int n = blockIdx.x;
  int e = threadIdx.x;
  float s[T_TOKN];
  float m = -1e30f;
#pragma unroll
  for (int t = 0; t < T_TOKN; ++t) { s[t] = scores[t * NUNITS + n]; m = fmaxf(m, s[t]); }
  float sum = 0.f;
#pragma unroll
  for (int t = 0; t < T_TOKN; ++t) { s[t] = expf(s[t] - m); sum += s[t]; }
  float inv = 1.f / sum;
  float a = 0.f;
#pragma unroll
  for (int t = 0; t < T_TOKN; ++t)
    a += s[t] * inv * bf2f(out_lin[((size_t)t * NUNITS + n) * 128 + e]);
  tok_feat[n * 128 + e] = a;
}

// ---------------------------------------------------------------------------
extern "C" void kernel_launch(void* const* d_in, const int* in_sizes, int n_in,
                              void* d_out, int out_size, void* d_ws, size_t ws_size,
                              hipStream_t stream)
{
  const int*   units = (const int*)d_in[0];
  const int*   paths = (const int*)d_in[1];
  const int*   upd   = (const int*)d_in[2];
  const int*   ppd   = (const int*)d_in[3];
  const float* emb   = (const float*)d_in[4];
  const float* tWif  = (const float*)d_in[5];
  const float* tWhf  = (const float*)d_in[6];
  const float* tbf   = (const float*)d_in[7];
  const float* tWib  = (const float*)d_in[8];
  const float* tWhb  = (const float*)d_in[9];
  const float* tbb   = (const float*)d_in[10];
  const float* linW  = (const float*)d_in[11];
  const float* linb  = (const float*)d_in[12];
  const float* lng   = (const float*)d_in[13];
  const float* lnb   = (const float*)d_in[14];
  const float* attw  = (const float*)d_in[15];
  const float* attb  = (const float*)d_in[16];
  const float* pWif  = (const float*)d_in[17];
  const float* pWhf  = (const float*)d_in[18];
  const float* pbf   = (const float*)d_in[19];
  const float* pWib  = (const float*)d_in[20];
  const float* pWhb  = (const float*)d_in[21];
  const float* pbb   = (const float*)d_in[22];
  const float* ulW   = (const float*)d_in[23];
  const float* ulb   = (const float*)d_in[24];

  float* ws = (float*)d_ws;
  int*   ip = (int*)(ws + OFF_INT);
  if (ws_size < WS_FLOATS * sizeof(float)) return;

  unsigned short* wfrag   = (unsigned short*)(ws + OFF_WFRAG);
  unsigned short* linfrag = (unsigned short*)(ws + OFF_LINFRAG);
  unsigned short* ulfrag  = linfrag + 32768;
  unsigned short* OUTF  = (unsigned short*)(ws + OFF_OUTF);
  unsigned short* OUTB  = (unsigned short*)(ws + OFF_OUTB);
  unsigned short* POUTF = (unsigned short*)(ws + OFF_POUTF);
  unsigned short* POUTB = (unsigned short*)(ws + OFF_POUTB);

  prep_kernel<<<2324, 256, 0, stream>>>(tWif, tWhf, tWib, tWhb,
                                        pWif, pWhf, pWib, pWhb,
                                        linW, ulW, units, paths, upd, ppd,
                                        ws, ip);

  lstm_kernel<0><<<dim3(128, 2), 1024, 0, stream>>>(
      wfrag, tbf, tbb, emb, units, ip /*tok_len*/, nullptr, nullptr, nullptr,
      OUTF, OUTB);

  gemm_mfma<1><<<1024, 256, 0, stream>>>(
      OUTF, OUTB, ip /*tok_len*/, linfrag, linb,
      (void*)(ws + OFF_OUTLIN), ws + OFF_SCORES, lng, lnb, attw, attb, units, NUNITS);

  softmax_feat_kernel<<<4096, 128, 0, stream>>>(
      ws + OFF_SCORES, (const unsigned short*)(ws + OFF_OUTLIN),
      ws + OFF_TOKFEAT);

  lstm_kernel<1><<<dim3(128, 2), 1024, 0, stream>>>(
      wfrag, pbf, pbb, ws + OFF_TOKFEAT, paths, ip + 5120 /*p_len*/,
      ip + 4096 /*fe*/, ip + 6144 /*off_p*/, ip + 7168 /*un_p*/,
      POUTF, POUTB);

  gemm_mfma<0><<<512, 256, 0, stream>>>(
      POUTF, POUTB, ip + 5120 /*p_len*/, ulfrag, ulb,
      (void*)d_out, nullptr, nullptr, nullptr, nullptr, nullptr, nullptr, NPATHS);
}